// Round 7
// baseline (2288.098 us; speedup 1.0000x reference)
//
#include <hip/hip_runtime.h>
#include <hip/hip_bf16.h>
#include <float.h>

// ---------------------------------------------------------------------------
// ImprovedTransformerGNN: fp32 compute, bf16 gather table for aggregation.
// N=50000, E=600000, H=128, IN=128, C=4, L=3, G=128.
// R6 (resubmit; prior round hit GPU-acquisition timeout): gemm_fused reshaped
//     for occupancy: 64 rows/block (782 blocks = 3 waves/SIMD device-wide,
//     was 1.5), 32 colgrps x CPT=M/32, W staged in two 32KB k-halves
//     (4+ blocks/CU residency, was 2). R=8 rows/ds_read keeps LDS pipe at
//     2x headroom.
// ---------------------------------------------------------------------------

#define GGRAPHS 128
#define POOL_NC 16

__device__ __forceinline__ float gelu_f(float x) {
    return 0.5f * x * (1.0f + erff(x * 0.7071067811865476f));
}

__device__ __forceinline__ unsigned short f2bf(float f) {  // RNE, finite inputs
    unsigned int u = __float_as_uint(f);
    unsigned int r = (u + 0x7FFFu + ((u >> 16) & 1u)) >> 16;
    return (unsigned short)r;
}

__device__ __forceinline__ float bf2f(unsigned short u) {
    return __uint_as_float(((unsigned int)u) << 16);
}

static constexpr float BNS_F = 0.99999500003749968f;  // 1/sqrt(1+1e-5)

// ---------------------------------------------------------------------------
// Fused GEMM: Y[nrows,M] = act( (X[nrows,128] @ W[128,M]) * sc + bi ) (+resid)
// Block: 256 threads, 64 rows. colgrp=tid&31 (32 x CPT cols), rowgrp=tid>>5
// (8 x 8 rows). W staged in two 64-krow halves (32KB for M=128) -> 4 blocks/CU.
// Per kk: 1 LDS b128 (b64) read reused across 8 rows -> VALU-bound.
// In-place X==Y safe (each row read/written by exactly one thread; clamped
// tail reads discarded by the r<nrows store guard).
// DO_AW: emit aw instead of Y. DO_BF16: also write bf16 Y (gather table).
// ---------------------------------------------------------------------------
template<int M, bool DO_BN, bool DO_GELU, bool DO_RES, bool DO_AW, bool DO_BF16>
__global__ __launch_bounds__(256, 4)
void gemm_fused(const float* __restrict__ X, const float* __restrict__ W,
                const float* __restrict__ bias, const float* __restrict__ gam,
                const float* __restrict__ beta, const float* __restrict__ resid,
                float* __restrict__ Y, ushort4* __restrict__ Ybf,
                const float* __restrict__ Wa2, const float* __restrict__ ba2,
                float* __restrict__ awout, int nrows)
{
    constexpr int CPT = M / 32;   // 4 (M=128) or 2 (M=64)
    constexpr int NF4 = M / 4;    // float4 per k-row (global W)
    __shared__ float Wsf[64 * M]; // 32KB (M=128) / 16KB (M=64)

    const int tid = threadIdx.x;
    const int colgrp = tid & 31;
    const int rowgrp = tid >> 5;            // 0..7
    const int r0 = blockIdx.x * 64 + rowgrp * 8;

    float acc[8][CPT];
#pragma unroll
    for (int i = 0; i < 8; ++i)
#pragma unroll
        for (int j = 0; j < CPT; ++j) acc[i][j] = 0.f;

    // per-row float4 offsets into X (clamped; clamped rows never stored)
    const float4* __restrict__ X4 = reinterpret_cast<const float4*>(X);
    int off[8];
#pragma unroll
    for (int i = 0; i < 8; ++i) {
        int r = r0 + i; if (r >= nrows) r = nrows - 1;
        off[i] = r * 32;
    }
    float4 xv[8];
#pragma unroll
    for (int i = 0; i < 8; ++i) xv[i] = X4[off[i]];

    float4* Ws4 = reinterpret_cast<float4*>(Wsf);
    const float4* W4 = reinterpret_cast<const float4*>(W);

    for (int half = 0; half < 2; ++half) {
        __syncthreads();  // half 1: protect Ws while still in use
#pragma unroll
        for (int i = 0; i < (64 * NF4) / 256; ++i)
            Ws4[tid + i * 256] = W4[half * (64 * NF4) + tid + i * 256];
        __syncthreads();

        for (int k4 = 0; k4 < 16; ++k4) {
            const int k4g = half * 16 + k4;
            float4 xn[8];
            if (k4g < 31) {
#pragma unroll
                for (int i = 0; i < 8; ++i) xn[i] = X4[off[i] + k4g + 1];
            }
#pragma unroll
            for (int kk = 0; kk < 4; ++kk) {
                const int k = k4 * 4 + kk;   // local k within half
                if constexpr (CPT == 4) {
                    const float4 w0 = *reinterpret_cast<const float4*>(&Wsf[k * M + 4 * colgrp]);
#pragma unroll
                    for (int i = 0; i < 8; ++i) {
                        const float xs = reinterpret_cast<const float*>(&xv[i])[kk];
                        acc[i][0] = fmaf(xs, w0.x, acc[i][0]);
                        acc[i][1] = fmaf(xs, w0.y, acc[i][1]);
                        acc[i][2] = fmaf(xs, w0.z, acc[i][2]);
                        acc[i][3] = fmaf(xs, w0.w, acc[i][3]);
                    }
                } else {
                    const float2 w0 = *reinterpret_cast<const float2*>(&Wsf[k * M + 2 * colgrp]);
#pragma unroll
                    for (int i = 0; i < 8; ++i) {
                        const float xs = reinterpret_cast<const float*>(&xv[i])[kk];
                        acc[i][0] = fmaf(xs, w0.x, acc[i][0]);
                        acc[i][1] = fmaf(xs, w0.y, acc[i][1]);
                    }
                }
            }
            if (k4g < 31) {
#pragma unroll
                for (int i = 0; i < 8; ++i) xv[i] = xn[i];
            }
        }
    }

    // epilogue: per-column scale/bias (BN folded), gelu, residual / aw
    const int cb = CPT * colgrp;
    float scA[CPT], biA[CPT];
#pragma unroll
    for (int j = 0; j < CPT; ++j) {
        const int c = cb + j;
        if (DO_BN) { float g = gam[c]; scA[j] = g * BNS_F; biA[j] = bias[c] * scA[j] + beta[c]; }
        else       { scA[j] = 1.f;     biA[j] = bias[c]; }
    }

    if (DO_AW) {
        // M=64, CPT=2: aw[r] = tanh( gelu(row) . Wa2 + ba2 )
        float wa[CPT];
#pragma unroll
        for (int j = 0; j < CPT; ++j) wa[j] = Wa2[cb + j];
        const float ba2v = ba2[0];
#pragma unroll
        for (int i = 0; i < 8; ++i) {
            float p = 0.f;
#pragma unroll
            for (int j = 0; j < CPT; ++j) {
                float v = acc[i][j] * scA[j] + biA[j];
                if (DO_GELU) v = gelu_f(v);
                p = fmaf(v, wa[j], p);
            }
            p += __shfl_xor(p, 1);
            p += __shfl_xor(p, 2);
            p += __shfl_xor(p, 4);
            p += __shfl_xor(p, 8);
            p += __shfl_xor(p, 16);
            const int r = r0 + i;
            if (colgrp == 0 && r < nrows) awout[r] = tanhf(p + ba2v);
        }
        return;
    }

#pragma unroll
    for (int i = 0; i < 8; ++i) {
        const int r = r0 + i;
        if (r < nrows) {
            float o[CPT];
#pragma unroll
            for (int j = 0; j < CPT; ++j) {
                float v = acc[i][j] * scA[j] + biA[j];
                if (DO_GELU) v = gelu_f(v);
                if (DO_RES) v += resid[(size_t)r * M + cb + j];
                o[j] = v;
            }
            if constexpr (CPT == 4) {
                float4 o4; o4.x = o[0]; o4.y = o[1]; o4.z = o[2]; o4.w = o[3];
                *reinterpret_cast<float4*>(Y + (size_t)r * M + cb) = o4;
                if (DO_BF16) {
                    ushort4 q;
                    q.x = f2bf(o[0]); q.y = f2bf(o[1]); q.z = f2bf(o[2]); q.w = f2bf(o[3]);
                    Ybf[(size_t)r * 32 + colgrp] = q;
                }
            } else {
                float2 o2; o2.x = o[0]; o2.y = o[1];
                *reinterpret_cast<float2*>(Y + (size_t)r * M + cb) = o2;
            }
        }
    }
}

// ---------------------------------------------------------------------------
// CSR build: count + per-edge rank (atomic), scan (+dinv), atomic-free fill.
// ---------------------------------------------------------------------------
__global__ void count_rank_kernel(const int* __restrict__ dst, int* __restrict__ cnt,
                                  int* __restrict__ rank, int E)
{
    int e = blockIdx.x * 256 + threadIdx.x;
    if (e < E) rank[e] = atomicAdd(&cnt[dst[e]], 1);
}

// 3-phase parallel scan; also emits dinv = rsqrt(deg+1)
__global__ void scan_local(const int* __restrict__ cnt, int* __restrict__ rowptr,
                           int* __restrict__ bsum, float* __restrict__ dinv, int n)
{
    __shared__ int sd[1024];
    const int tid = threadIdx.x;
    const int i = blockIdx.x * 1024 + tid;
    int v = (i < n) ? cnt[i] : 0;
    if (i < n) dinv[i] = rsqrtf((float)v + 1.0f);
    sd[tid] = v;
    __syncthreads();
    for (int off = 1; off < 1024; off <<= 1) {
        int t = (tid >= off) ? sd[tid - off] : 0;
        __syncthreads();
        sd[tid] += t;
        __syncthreads();
    }
    if (i < n) rowptr[i + 1] = sd[tid];
    if (tid == 1023) bsum[blockIdx.x] = sd[1023];
}

__global__ void scan_bsum(int* __restrict__ bsum, int nb)
{
    const int lane = threadIdx.x;  // 64 threads, nb <= 64
    int orig = (lane < nb) ? bsum[lane] : 0;
    int v = orig;
#pragma unroll
    for (int off = 1; off < 64; off <<= 1) {
        int t = __shfl_up(v, off);
        if (lane >= off) v += t;
    }
    if (lane < nb) bsum[lane] = v - orig;  // exclusive prefix
}

__global__ void scan_add(int* __restrict__ rowptr, const int* __restrict__ bsum, int n)
{
    const int i = blockIdx.x * 1024 + threadIdx.x;
    if (i < n) rowptr[i + 1] += bsum[blockIdx.x];
    if (i == 0) rowptr[0] = 0;
}

// atomic-free fill: pos = rowptr[dst] + rank[e]; interleaved (src, w) 8B store
__global__ void fill_kernel(const int* __restrict__ src, const int* __restrict__ dst,
                            const float* __restrict__ dinv, const int* __restrict__ rowptr,
                            const int* __restrict__ rank, int2* __restrict__ csr, int E)
{
    int e = blockIdx.x * 256 + threadIdx.x;
    if (e < E) {
        const int d = dst[e], s = src[e];
        const int pos = rowptr[d] + rank[e];
        int2 p;
        p.x = s;
        p.y = __float_as_int(dinv[s] * dinv[d]);
        csr[pos] = p;
    }
}

// ---------------------------------------------------------------------------
// Aggregation (gather over CSR, bf16 rows): ah = h*snorm + sum h[src]*w
// 32 threads/node (ushort4 lanes = 8B), 8 nodes/block, 4-edge unroll.
// fp32 accumulate.
// ---------------------------------------------------------------------------
#define FMAB(A, Wt, U) { A.x = fmaf(Wt, bf2f(U.x), A.x); A.y = fmaf(Wt, bf2f(U.y), A.y); \
                         A.z = fmaf(Wt, bf2f(U.z), A.z); A.w = fmaf(Wt, bf2f(U.w), A.w); }

__global__ __launch_bounds__(256)
void agg_kernel(const ushort4* __restrict__ hb, const int2* __restrict__ csr,
                const int* __restrict__ rowptr, const float* __restrict__ dinv,
                float* __restrict__ ah, int n)
{
    const int node = blockIdx.x * 8 + (threadIdx.x >> 5);
    if (node >= n) return;
    const int lane = threadIdx.x & 31;  // ushort4 index within the 128-wide row

    const float di = dinv[node];
    const float sw = di * di;
    const ushort4 sv = hb[(size_t)node * 32 + lane];
    float4 a0, a1;
    a0.x = bf2f(sv.x) * sw; a0.y = bf2f(sv.y) * sw;
    a0.z = bf2f(sv.z) * sw; a0.w = bf2f(sv.w) * sw;
    a1.x = 0.f; a1.y = 0.f; a1.z = 0.f; a1.w = 0.f;

    const int beg = rowptr[node], end = rowptr[node + 1];
    int s = beg;
    for (; s + 4 <= end; s += 4) {
        const int2 e0 = csr[s+0], e1 = csr[s+1], e2 = csr[s+2], e3 = csr[s+3];
        const ushort4 v0 = hb[(size_t)e0.x * 32 + lane];
        const ushort4 v1 = hb[(size_t)e1.x * 32 + lane];
        const ushort4 v2 = hb[(size_t)e2.x * 32 + lane];
        const ushort4 v3 = hb[(size_t)e3.x * 32 + lane];
        FMAB(a0, __int_as_float(e0.y), v0); FMAB(a1, __int_as_float(e1.y), v1);
        FMAB(a0, __int_as_float(e2.y), v2); FMAB(a1, __int_as_float(e3.y), v3);
    }
    for (; s < end; ++s) {
        const int2 e0 = csr[s];
        const ushort4 v = hb[(size_t)e0.x * 32 + lane];
        FMAB(a0, __int_as_float(e0.y), v);
    }
    float4 o;
    o.x = a0.x + a1.x; o.y = a0.y + a1.y; o.z = a0.z + a1.z; o.w = a0.w + a1.w;
    reinterpret_cast<float4*>(ah)[(size_t)node * 32 + lane] = o;
}

// ---------------------------------------------------------------------------
// batch is sorted: per-graph boundaries via binary search
// ---------------------------------------------------------------------------
__global__ void bounds_kernel(const int* __restrict__ batch, int* __restrict__ bound, int n, int g)
{
    const int t = blockIdx.x * blockDim.x + threadIdx.x;
    if (t > g) return;
    int lo = 0, hi = n;
    while (lo < hi) { int mid = (lo + hi) >> 1; if (batch[mid] < t) lo = mid + 1; else hi = mid; }
    bound[t] = lo;
}

// ---------------------------------------------------------------------------
// 2-stage deterministic pooling. Stage 1: 16 fixed chunks per graph.
// ---------------------------------------------------------------------------
__global__ void pool_partial(const float* __restrict__ h, const float* __restrict__ aw,
                             const int* __restrict__ bound, float* __restrict__ ps,
                             float* __restrict__ pm, float* __restrict__ pw)
{
    const int g = blockIdx.x >> 4;
    const int c = blockIdx.x & (POOL_NC - 1);
    const int f = threadIdx.x;  // 128 threads
    const int beg = bound[g], end = bound[g + 1];
    const int len = end - beg;
    const int cbeg = beg + (int)(((long long)len * c) / POOL_NC);
    const int cend = beg + (int)(((long long)len * (c + 1)) / POOL_NC);
    float s = 0.f, m = -FLT_MAX, w = 0.f;
    for (int node = cbeg; node < cend; ++node) {
        const float v = h[(size_t)node * 128 + f];
        const float a = aw[node];
        s += v;
        m = fmaxf(m, v);
        w = fmaf(v, a, w);
    }
    const size_t idx = ((size_t)g * POOL_NC + c) * 128 + f;
    ps[idx] = s; pm[idx] = m; pw[idx] = w;
}

__global__ void pool_final(const float* __restrict__ ps, const float* __restrict__ pm,
                           const float* __restrict__ pw, const int* __restrict__ bound,
                           float* __restrict__ comb)
{
    const int g = blockIdx.x;
    const int f = threadIdx.x;  // 128 threads
    float s = 0.f, m = -FLT_MAX, w = 0.f;
#pragma unroll
    for (int c = 0; c < POOL_NC; ++c) {
        const size_t idx = ((size_t)g * POOL_NC + c) * 128 + f;
        s += ps[idx];
        m = fmaxf(m, pm[idx]);
        w += pw[idx];
    }
    float cn = (float)(bound[g + 1] - bound[g]);
    if (cn < 1.f) cn = 1.f;
    comb[(size_t)g * 512 + f]       = s / cn;
    comb[(size_t)g * 512 + 128 + f] = m;
    comb[(size_t)g * 512 + 256 + f] = s / cn;
    comb[(size_t)g * 512 + 384 + f] = w / cn;
}

// ---------------------------------------------------------------------------
// classifier head GEMM: grid = G * (M/64); block 256 = 64 cols x 4 k-quarters.
// ---------------------------------------------------------------------------
template<int K, int M, bool DO_BN, bool DO_GELU>
__global__ __launch_bounds__(256)
void rowgemm2(const float* __restrict__ X, const float* __restrict__ W,
              const float* __restrict__ bias, const float* __restrict__ gam,
              const float* __restrict__ beta, float* __restrict__ Y)
{
    constexpr int NC = M / 64;
    constexpr int KQ = K / 4;
    const int row = blockIdx.x / NC;
    const int lane = threadIdx.x & 63;
    const int c = (blockIdx.x % NC) * 64 + lane;
    const int q = threadIdx.x >> 6;  // k-quarter 0..3

    const float* __restrict__ xq = X + (size_t)row * K + q * KQ;
    const float* __restrict__ wq = W + (size_t)(q * KQ) * M + c;

    float a0 = 0.f, a1 = 0.f, a2 = 0.f, a3 = 0.f;
#pragma unroll 4
    for (int k = 0; k < KQ; k += 4) {
        const float4 xv = *reinterpret_cast<const float4*>(xq + k);
        a0 = fmaf(xv.x, wq[(size_t)(k + 0) * M], a0);
        a1 = fmaf(xv.y, wq[(size_t)(k + 1) * M], a1);
        a2 = fmaf(xv.z, wq[(size_t)(k + 2) * M], a2);
        a3 = fmaf(xv.w, wq[(size_t)(k + 3) * M], a3);
    }
    __shared__ float part[4][64];
    part[q][lane] = (a0 + a1) + (a2 + a3);
    __syncthreads();
    if (q == 0) {
        float v = (part[0][lane] + part[1][lane]) + (part[2][lane] + part[3][lane]);
        if (DO_BN) { const float g = gam[c]; const float sc = g * BNS_F; v = v * sc + (bias[c] * sc + beta[c]); }
        else       { v = v + bias[c]; }
        if (DO_GELU) v = gelu_f(v);
        Y[(size_t)row * M + c] = v;
    }
}

// final layer: [G,64] @ [64,4] + bias; one wave per row, shuffle reduce
__global__ void rowgemm_final(const float* __restrict__ X, const float* __restrict__ W,
                              const float* __restrict__ bias, float* __restrict__ Y)
{
    const int row = blockIdx.x;
    const int lane = threadIdx.x;  // 64
    const float xv = X[(size_t)row * 64 + lane];
    const float4 wr = *reinterpret_cast<const float4*>(W + lane * 4);
    float a0 = xv * wr.x, a1 = xv * wr.y, a2 = xv * wr.z, a3 = xv * wr.w;
#pragma unroll
    for (int off = 32; off; off >>= 1) {
        a0 += __shfl_xor(a0, off);
        a1 += __shfl_xor(a1, off);
        a2 += __shfl_xor(a2, off);
        a3 += __shfl_xor(a3, off);
    }
    if (lane == 0) {
        Y[(size_t)row * 4 + 0] = a0 + bias[0];
        Y[(size_t)row * 4 + 1] = a1 + bias[1];
        Y[(size_t)row * 4 + 2] = a2 + bias[2];
        Y[(size_t)row * 4 + 3] = a3 + bias[3];
    }
}

// ---------------------------------------------------------------------------
extern "C" void kernel_launch(void* const* d_in, const int* in_sizes, int n_in,
                              void* d_out, int out_size, void* d_ws, size_t ws_size,
                              hipStream_t stream)
{
    const float* x     = (const float*)d_in[0];
    const int*   ei    = (const int*)d_in[1];
    const int*   batch = (const int*)d_in[2];
    const float* W1  = (const float*)d_in[3];
    const float* b1  = (const float*)d_in[4];
    const float* g1  = (const float*)d_in[5];
    const float* be1 = (const float*)d_in[6];
    const float* W2  = (const float*)d_in[7];
    const float* b2  = (const float*)d_in[8];
    const float* g2  = (const float*)d_in[9];
    const float* be2 = (const float*)d_in[10];
    const float* Wg  = (const float*)d_in[11];
    const float* bg  = (const float*)d_in[12];
    const float* gg  = (const float*)d_in[13];
    const float* bgg = (const float*)d_in[14];
    const float* Wa1 = (const float*)d_in[15];
    const float* ba1 = (const float*)d_in[16];
    const float* Wa2 = (const float*)d_in[17];
    const float* ba2 = (const float*)d_in[18];
    const float* Wc1 = (const float*)d_in[19];
    const float* bc1 = (const float*)d_in[20];
    const float* gc1 = (const float*)d_in[21];
    const float* bec1= (const float*)d_in[22];
    const float* Wc2 = (const float*)d_in[23];
    const float* bc2 = (const float*)d_in[24];
    const float* gc2 = (const float*)d_in[25];
    const float* bec2= (const float*)d_in[26];
    const float* Wc3 = (const float*)d_in[27];
    const float* bc3 = (const float*)d_in[28];
    const float* gc3 = (const float*)d_in[29];
    const float* bec3= (const float*)d_in[30];
    const float* Wc4 = (const float*)d_in[31];
    const float* bc4 = (const float*)d_in[32];
    float* out = (float*)d_out;

    const int N = in_sizes[0] / 128;
    const int E = in_sizes[1] / 2;
    const int G = GGRAPHS;

    // workspace carve-up
    size_t off = 0;
    auto alloc = [&](size_t bytes) -> void* {
        void* p = (char*)d_ws + off;
        off += (bytes + 255) & ~(size_t)255;
        return p;
    };
    float*   hA     = (float*)alloc((size_t)N * 128 * 4);
    float*   hB     = (float*)alloc((size_t)N * 128 * 4);
    ushort4* hbf    = (ushort4*)alloc((size_t)N * 128 * 2);
    float*   aw     = (float*)alloc((size_t)N * 4);
    float*   dinv   = (float*)alloc((size_t)N * 4);
    int*     cnt    = (int*)alloc((size_t)N * 4);
    int*     rank   = (int*)alloc((size_t)E * 4);
    int*     rowptr = (int*)alloc((size_t)(N + 1) * 4);
    int*     bsum   = (int*)alloc(64 * 4);
    int2*    csr    = (int2*)alloc((size_t)E * 8);
    int*     bound  = (int*)alloc((size_t)(G + 1) * 4);
    float*   comb   = (float*)alloc((size_t)G * 512 * 4);
    float*   ps     = (float*)alloc((size_t)G * POOL_NC * 128 * 4);
    float*   pm     = (float*)alloc((size_t)G * POOL_NC * 128 * 4);
    float*   pw     = (float*)alloc((size_t)G * POOL_NC * 128 * 4);
    float*   z1     = (float*)alloc((size_t)G * 256 * 4);
    float*   z2     = (float*)alloc((size_t)G * 128 * 4);
    float*   z3     = (float*)alloc((size_t)G * 64 * 4);
    (void)ws_size;

    const int* e_src = ei;
    const int* e_dst = ei + E;

    // ---- CSR build over dst (reused by all 3 GCN layers) ----
    hipMemsetAsync(cnt, 0, (size_t)N * 4, stream);
    count_rank_kernel<<<(E + 255) / 256, 256, 0, stream>>>(e_dst, cnt, rank, E);
    const int nb = (N + 1023) / 1024;
    scan_local<<<nb, 1024, 0, stream>>>(cnt, rowptr, bsum, dinv, N);
    scan_bsum<<<1, 64, 0, stream>>>(bsum, nb);
    scan_add<<<nb, 1024, 0, stream>>>(rowptr, bsum, N);
    fill_kernel<<<(E + 255) / 256, 256, 0, stream>>>(e_src, e_dst, dinv, rowptr, rank, csr, E);

    const int gblocks = (N + 63) / 64;

    // ---- input projection ----
    gemm_fused<128, true, true, false, false, false><<<gblocks, 256, 0, stream>>>(
        x,  W1, b1, g1, be1, nullptr, hA, nullptr, nullptr, nullptr, nullptr, N);
    gemm_fused<128, true, true, false, false, true><<<gblocks, 256, 0, stream>>>(
        hA, W2, b2, g2, be2, nullptr, hA, hbf, nullptr, nullptr, nullptr, N);

    // ---- GCN layers: aggregate-then-transform (linearity) ----
    for (int l = 0; l < 3; ++l) {
        agg_kernel<<<(N + 7) / 8, 256, 0, stream>>>(hbf, csr, rowptr, dinv, hB, N);
        if (l < 2) {
            gemm_fused<128, true, true, true, false, true><<<gblocks, 256, 0, stream>>>(
                hB, Wg + (size_t)l * 128 * 128, bg + (size_t)l * 128,
                gg + (size_t)l * 128, bgg + (size_t)l * 128, hA, hA, hbf,
                nullptr, nullptr, nullptr, N);
        } else {
            gemm_fused<128, true, true, true, false, false><<<gblocks, 256, 0, stream>>>(
                hB, Wg + (size_t)l * 128 * 128, bg + (size_t)l * 128,
                gg + (size_t)l * 128, bgg + (size_t)l * 128, hA, hA, nullptr,
                nullptr, nullptr, nullptr, N);
        }
    }

    // ---- attention weights (fused: gelu(h@Wa1+ba1)@Wa2+ba2 -> tanh) ----
    gemm_fused<64, false, true, false, true, false><<<gblocks, 256, 0, stream>>>(
        hA, Wa1, ba1, nullptr, nullptr, nullptr, nullptr, nullptr, Wa2, ba2, aw, N);

    // ---- pooling ----
    bounds_kernel<<<1, 256, 0, stream>>>(batch, bound, N, G);
    pool_partial<<<G * POOL_NC, 128, 0, stream>>>(hA, aw, bound, ps, pm, pw);
    pool_final<<<G, 128, 0, stream>>>(ps, pm, pw, bound, comb);

    // ---- classifier head ----
    rowgemm2<512, 256, true, true><<<G * 4, 256, 0, stream>>>(comb, Wc1, bc1, gc1, bec1, z1);
    rowgemm2<256, 128, true, true><<<G * 2, 256, 0, stream>>>(z1, Wc2, bc2, gc2, bec2, z2);
    rowgemm2<128, 64,  true, true><<<G * 1, 256, 0, stream>>>(z2, Wc3, bc3, gc3, bec3, z3);
    rowgemm_final<<<G, 64, 0, stream>>>(z3, Wc4, bc4, out);
}

// Round 8
// 544.950 us; speedup vs baseline: 4.1987x; 4.1987x over previous
//
#include <hip/hip_runtime.h>
#include <hip/hip_bf16.h>
#include <float.h>

// ---------------------------------------------------------------------------
// ImprovedTransformerGNN: fp32 compute, bf16 gather table for aggregation.
// N=50000, E=600000, H=128, IN=128, C=4, L=3, G=128.
// R8: column-split GEMM (128 rows x 64 cols per block, 32KB W-tile, acc[8][4]
//     = 32 regs, grid 782) under launch_bounds(256,2) -- occupancy via
//     pressure reduction, NOT a VGPR cap (R6's (256,4) cap => 64 regs =>
//     scratch spill => 1GB/dispatch, 400us). Ping-pong hA/hB (col-split
//     breaks in-place X==Y).
// ---------------------------------------------------------------------------

#define GGRAPHS 128
#define POOL_NC 16

__device__ __forceinline__ float gelu_f(float x) {
    return 0.5f * x * (1.0f + erff(x * 0.7071067811865476f));
}

__device__ __forceinline__ unsigned short f2bf(float f) {  // RNE, finite inputs
    unsigned int u = __float_as_uint(f);
    unsigned int r = (u + 0x7FFFu + ((u >> 16) & 1u)) >> 16;
    return (unsigned short)r;
}

__device__ __forceinline__ float bf2f(unsigned short u) {
    return __uint_as_float(((unsigned int)u) << 16);
}

static constexpr float BNS_F = 0.99999500003749968f;  // 1/sqrt(1+1e-5)

// ---------------------------------------------------------------------------
// Fused GEMM, column-split: each block computes 128 rows x 64 cols of
// Y[nrows,M] = act( (X[nrows,128] @ W[128,M]) * sc + bi ) (+resid).
// grid = rowblocks * (M/64). colblk = blockIdx.x % (M/64).
// Block: 256 threads = 16 colgrps (tid&15, 4 cols each) x 16 rowgrps
// (tid>>4, 8 rows each). W-tile [128][64] = 32KB LDS, staged once.
// Per kk: 1 ds_read_b128 reused across 8 rows (R=8, LDS pipe 5x headroom).
// acc[8][4]=32 regs + xv/xn prefetch ~= 100 VGPRs (R5-proven pattern).
// X != Y required (col-split: another block reads X rows this block writes).
// resid may equal Y (col-local, same-thread read-before-write).
// DO_AW (M=64 only): emit aw[r]=tanh(gelu(row)@Wa2+ba2) instead of Y.
// ---------------------------------------------------------------------------
template<int M, bool DO_BN, bool DO_GELU, bool DO_RES, bool DO_AW, bool DO_BF16>
__global__ __launch_bounds__(256, 2)
void gemm_fused(const float* __restrict__ X, const float* __restrict__ W,
                const float* __restrict__ bias, const float* __restrict__ gam,
                const float* __restrict__ beta, const float* __restrict__ resid,
                float* __restrict__ Y, ushort4* __restrict__ Ybf,
                const float* __restrict__ Wa2, const float* __restrict__ ba2,
                float* __restrict__ awout, int nrows)
{
    constexpr int NCB = M / 64;   // column blocks (2 for M=128, 1 for M=64)
    __shared__ float Wsf[128 * 64];   // 32KB

    const int tid = threadIdx.x;
    const int rowblk = (int)blockIdx.x / NCB;
    const int colblk = (int)blockIdx.x % NCB;

    // ---- stage W cols [colblk*64, +64) for all 128 k ----
    float4* Ws4 = reinterpret_cast<float4*>(Wsf);
    const float4* W4 = reinterpret_cast<const float4*>(W);
#pragma unroll
    for (int i = 0; i < 8; ++i) {
        const int idx = i * 256 + tid;          // 0..2047
        Ws4[idx] = W4[(size_t)(idx >> 4) * (M / 4) + colblk * 16 + (idx & 15)];
    }
    __syncthreads();

    const int colgrp = tid & 15;
    const int rowgrp = tid >> 4;
    const int r0 = rowblk * 128 + rowgrp * 8;

    float acc[8][4];
#pragma unroll
    for (int i = 0; i < 8; ++i)
#pragma unroll
        for (int j = 0; j < 4; ++j) acc[i][j] = 0.f;

    const float4* __restrict__ X4 = reinterpret_cast<const float4*>(X);
    int off[8];
#pragma unroll
    for (int i = 0; i < 8; ++i) {
        int r = r0 + i; if (r >= nrows) r = nrows - 1;
        off[i] = r * 32;
    }
    float4 xv[8];
#pragma unroll
    for (int i = 0; i < 8; ++i) xv[i] = X4[off[i]];

    for (int k4 = 0; k4 < 32; ++k4) {
        float4 xn[8];
        if (k4 < 31) {
#pragma unroll
            for (int i = 0; i < 8; ++i) xn[i] = X4[off[i] + k4 + 1];
        }
#pragma unroll
        for (int kk = 0; kk < 4; ++kk) {
            const int k = k4 * 4 + kk;
            const float4 w0 = *reinterpret_cast<const float4*>(&Wsf[k * 64 + 4 * colgrp]);
#pragma unroll
            for (int i = 0; i < 8; ++i) {
                const float xs = reinterpret_cast<const float*>(&xv[i])[kk];
                acc[i][0] = fmaf(xs, w0.x, acc[i][0]);
                acc[i][1] = fmaf(xs, w0.y, acc[i][1]);
                acc[i][2] = fmaf(xs, w0.z, acc[i][2]);
                acc[i][3] = fmaf(xs, w0.w, acc[i][3]);
            }
        }
        if (k4 < 31) {
#pragma unroll
            for (int i = 0; i < 8; ++i) xv[i] = xn[i];
        }
    }

    // epilogue: per-column scale/bias (BN folded), gelu, residual / aw
    const int cb = colblk * 64 + 4 * colgrp;
    float scA[4], biA[4];
#pragma unroll
    for (int j = 0; j < 4; ++j) {
        const int c = cb + j;
        if (DO_BN) { float g = gam[c]; scA[j] = g * BNS_F; biA[j] = bias[c] * scA[j] + beta[c]; }
        else       { scA[j] = 1.f;     biA[j] = bias[c]; }
    }

    if (DO_AW) {
        // M=64 (single col block): aw[r] = tanh( gelu(row) . Wa2 + ba2 )
        float wa[4];
#pragma unroll
        for (int j = 0; j < 4; ++j) wa[j] = Wa2[cb + j];
        const float ba2v = ba2[0];
#pragma unroll
        for (int i = 0; i < 8; ++i) {
            float p = 0.f;
#pragma unroll
            for (int j = 0; j < 4; ++j) {
                float v = acc[i][j] * scA[j] + biA[j];
                if (DO_GELU) v = gelu_f(v);
                p = fmaf(v, wa[j], p);
            }
            p += __shfl_xor(p, 1);
            p += __shfl_xor(p, 2);
            p += __shfl_xor(p, 4);
            p += __shfl_xor(p, 8);
            const int r = r0 + i;
            if (colgrp == 0 && r < nrows) awout[r] = tanhf(p + ba2v);
        }
        return;
    }

#pragma unroll
    for (int i = 0; i < 8; ++i) {
        const int r = r0 + i;
        if (r < nrows) {
            float4 o4; float* o = reinterpret_cast<float*>(&o4);
#pragma unroll
            for (int j = 0; j < 4; ++j) {
                float v = acc[i][j] * scA[j] + biA[j];
                if (DO_GELU) v = gelu_f(v);
                if (DO_RES) v += resid[(size_t)r * M + cb + j];
                o[j] = v;
            }
            *reinterpret_cast<float4*>(Y + (size_t)r * M + cb) = o4;
            if (DO_BF16) {
                ushort4 q;
                q.x = f2bf(o[0]); q.y = f2bf(o[1]); q.z = f2bf(o[2]); q.w = f2bf(o[3]);
                Ybf[(size_t)r * 32 + colblk * 16 + colgrp] = q;
            }
        }
    }
}

// ---------------------------------------------------------------------------
// CSR build: count + per-edge rank (atomic), scan (+dinv), atomic-free fill.
// ---------------------------------------------------------------------------
__global__ void count_rank_kernel(const int* __restrict__ dst, int* __restrict__ cnt,
                                  int* __restrict__ rank, int E)
{
    int e = blockIdx.x * 256 + threadIdx.x;
    if (e < E) rank[e] = atomicAdd(&cnt[dst[e]], 1);
}

// 3-phase parallel scan; also emits dinv = rsqrt(deg+1)
__global__ void scan_local(const int* __restrict__ cnt, int* __restrict__ rowptr,
                           int* __restrict__ bsum, float* __restrict__ dinv, int n)
{
    __shared__ int sd[1024];
    const int tid = threadIdx.x;
    const int i = blockIdx.x * 1024 + tid;
    int v = (i < n) ? cnt[i] : 0;
    if (i < n) dinv[i] = rsqrtf((float)v + 1.0f);
    sd[tid] = v;
    __syncthreads();
    for (int off = 1; off < 1024; off <<= 1) {
        int t = (tid >= off) ? sd[tid - off] : 0;
        __syncthreads();
        sd[tid] += t;
        __syncthreads();
    }
    if (i < n) rowptr[i + 1] = sd[tid];
    if (tid == 1023) bsum[blockIdx.x] = sd[1023];
}

__global__ void scan_bsum(int* __restrict__ bsum, int nb)
{
    const int lane = threadIdx.x;  // 64 threads, nb <= 64
    int orig = (lane < nb) ? bsum[lane] : 0;
    int v = orig;
#pragma unroll
    for (int off = 1; off < 64; off <<= 1) {
        int t = __shfl_up(v, off);
        if (lane >= off) v += t;
    }
    if (lane < nb) bsum[lane] = v - orig;  // exclusive prefix
}

__global__ void scan_add(int* __restrict__ rowptr, const int* __restrict__ bsum, int n)
{
    const int i = blockIdx.x * 1024 + threadIdx.x;
    if (i < n) rowptr[i + 1] += bsum[blockIdx.x];
    if (i == 0) rowptr[0] = 0;
}

// atomic-free fill: pos = rowptr[dst] + rank[e]; interleaved (src, w) 8B store
__global__ void fill_kernel(const int* __restrict__ src, const int* __restrict__ dst,
                            const float* __restrict__ dinv, const int* __restrict__ rowptr,
                            const int* __restrict__ rank, int2* __restrict__ csr, int E)
{
    int e = blockIdx.x * 256 + threadIdx.x;
    if (e < E) {
        const int d = dst[e], s = src[e];
        const int pos = rowptr[d] + rank[e];
        int2 p;
        p.x = s;
        p.y = __float_as_int(dinv[s] * dinv[d]);
        csr[pos] = p;
    }
}

// ---------------------------------------------------------------------------
// Aggregation (gather over CSR, bf16 rows): ah = h*snorm + sum h[src]*w
// 32 threads/node (ushort4 lanes = 8B), 8 nodes/block, 4-edge unroll.
// fp32 accumulate.
// ---------------------------------------------------------------------------
#define FMAB(A, Wt, U) { A.x = fmaf(Wt, bf2f(U.x), A.x); A.y = fmaf(Wt, bf2f(U.y), A.y); \
                         A.z = fmaf(Wt, bf2f(U.z), A.z); A.w = fmaf(Wt, bf2f(U.w), A.w); }

__global__ __launch_bounds__(256)
void agg_kernel(const ushort4* __restrict__ hb, const int2* __restrict__ csr,
                const int* __restrict__ rowptr, const float* __restrict__ dinv,
                float* __restrict__ ah, int n)
{
    const int node = blockIdx.x * 8 + (threadIdx.x >> 5);
    if (node >= n) return;
    const int lane = threadIdx.x & 31;  // ushort4 index within the 128-wide row

    const float di = dinv[node];
    const float sw = di * di;
    const ushort4 sv = hb[(size_t)node * 32 + lane];
    float4 a0, a1;
    a0.x = bf2f(sv.x) * sw; a0.y = bf2f(sv.y) * sw;
    a0.z = bf2f(sv.z) * sw; a0.w = bf2f(sv.w) * sw;
    a1.x = 0.f; a1.y = 0.f; a1.z = 0.f; a1.w = 0.f;

    const int beg = rowptr[node], end = rowptr[node + 1];
    int s = beg;
    for (; s + 4 <= end; s += 4) {
        const int2 e0 = csr[s+0], e1 = csr[s+1], e2 = csr[s+2], e3 = csr[s+3];
        const ushort4 v0 = hb[(size_t)e0.x * 32 + lane];
        const ushort4 v1 = hb[(size_t)e1.x * 32 + lane];
        const ushort4 v2 = hb[(size_t)e2.x * 32 + lane];
        const ushort4 v3 = hb[(size_t)e3.x * 32 + lane];
        FMAB(a0, __int_as_float(e0.y), v0); FMAB(a1, __int_as_float(e1.y), v1);
        FMAB(a0, __int_as_float(e2.y), v2); FMAB(a1, __int_as_float(e3.y), v3);
    }
    for (; s < end; ++s) {
        const int2 e0 = csr[s];
        const ushort4 v = hb[(size_t)e0.x * 32 + lane];
        FMAB(a0, __int_as_float(e0.y), v);
    }
    float4 o;
    o.x = a0.x + a1.x; o.y = a0.y + a1.y; o.z = a0.z + a1.z; o.w = a0.w + a1.w;
    reinterpret_cast<float4*>(ah)[(size_t)node * 32 + lane] = o;
}

// ---------------------------------------------------------------------------
// batch is sorted: per-graph boundaries via binary search
// ---------------------------------------------------------------------------
__global__ void bounds_kernel(const int* __restrict__ batch, int* __restrict__ bound, int n, int g)
{
    const int t = blockIdx.x * blockDim.x + threadIdx.x;
    if (t > g) return;
    int lo = 0, hi = n;
    while (lo < hi) { int mid = (lo + hi) >> 1; if (batch[mid] < t) lo = mid + 1; else hi = mid; }
    bound[t] = lo;
}

// ---------------------------------------------------------------------------
// 2-stage deterministic pooling. Stage 1: 16 fixed chunks per graph.
// ---------------------------------------------------------------------------
__global__ void pool_partial(const float* __restrict__ h, const float* __restrict__ aw,
                             const int* __restrict__ bound, float* __restrict__ ps,
                             float* __restrict__ pm, float* __restrict__ pw)
{
    const int g = blockIdx.x >> 4;
    const int c = blockIdx.x & (POOL_NC - 1);
    const int f = threadIdx.x;  // 128 threads
    const int beg = bound[g], end = bound[g + 1];
    const int len = end - beg;
    const int cbeg = beg + (int)(((long long)len * c) / POOL_NC);
    const int cend = beg + (int)(((long long)len * (c + 1)) / POOL_NC);
    float s = 0.f, m = -FLT_MAX, w = 0.f;
    for (int node = cbeg; node < cend; ++node) {
        const float v = h[(size_t)node * 128 + f];
        const float a = aw[node];
        s += v;
        m = fmaxf(m, v);
        w = fmaf(v, a, w);
    }
    const size_t idx = ((size_t)g * POOL_NC + c) * 128 + f;
    ps[idx] = s; pm[idx] = m; pw[idx] = w;
}

__global__ void pool_final(const float* __restrict__ ps, const float* __restrict__ pm,
                           const float* __restrict__ pw, const int* __restrict__ bound,
                           float* __restrict__ comb)
{
    const int g = blockIdx.x;
    const int f = threadIdx.x;  // 128 threads
    float s = 0.f, m = -FLT_MAX, w = 0.f;
#pragma unroll
    for (int c = 0; c < POOL_NC; ++c) {
        const size_t idx = ((size_t)g * POOL_NC + c) * 128 + f;
        s += ps[idx];
        m = fmaxf(m, pm[idx]);
        w += pw[idx];
    }
    float cn = (float)(bound[g + 1] - bound[g]);
    if (cn < 1.f) cn = 1.f;
    comb[(size_t)g * 512 + f]       = s / cn;
    comb[(size_t)g * 512 + 128 + f] = m;
    comb[(size_t)g * 512 + 256 + f] = s / cn;
    comb[(size_t)g * 512 + 384 + f] = w / cn;
}

// ---------------------------------------------------------------------------
// classifier head GEMM: grid = G * (M/64); block 256 = 64 cols x 4 k-quarters.
// ---------------------------------------------------------------------------
template<int K, int M, bool DO_BN, bool DO_GELU>
__global__ __launch_bounds__(256)
void rowgemm2(const float* __restrict__ X, const float* __restrict__ W,
              const float* __restrict__ bias, const float* __restrict__ gam,
              const float* __restrict__ beta, float* __restrict__ Y)
{
    constexpr int NC = M / 64;
    constexpr int KQ = K / 4;
    const int row = blockIdx.x / NC;
    const int lane = threadIdx.x & 63;
    const int c = (blockIdx.x % NC) * 64 + lane;
    const int q = threadIdx.x >> 6;  // k-quarter 0..3

    const float* __restrict__ xq = X + (size_t)row * K + q * KQ;
    const float* __restrict__ wq = W + (size_t)(q * KQ) * M + c;

    float a0 = 0.f, a1 = 0.f, a2 = 0.f, a3 = 0.f;
#pragma unroll 4
    for (int k = 0; k < KQ; k += 4) {
        const float4 xv = *reinterpret_cast<const float4*>(xq + k);
        a0 = fmaf(xv.x, wq[(size_t)(k + 0) * M], a0);
        a1 = fmaf(xv.y, wq[(size_t)(k + 1) * M], a1);
        a2 = fmaf(xv.z, wq[(size_t)(k + 2) * M], a2);
        a3 = fmaf(xv.w, wq[(size_t)(k + 3) * M], a3);
    }
    __shared__ float part[4][64];
    part[q][lane] = (a0 + a1) + (a2 + a3);
    __syncthreads();
    if (q == 0) {
        float v = (part[0][lane] + part[1][lane]) + (part[2][lane] + part[3][lane]);
        if (DO_BN) { const float g = gam[c]; const float sc = g * BNS_F; v = v * sc + (bias[c] * sc + beta[c]); }
        else       { v = v + bias[c]; }
        if (DO_GELU) v = gelu_f(v);
        Y[(size_t)row * M + c] = v;
    }
}

// final layer: [G,64] @ [64,4] + bias; one wave per row, shuffle reduce
__global__ void rowgemm_final(const float* __restrict__ X, const float* __restrict__ W,
                              const float* __restrict__ bias, float* __restrict__ Y)
{
    const int row = blockIdx.x;
    const int lane = threadIdx.x;  // 64
    const float xv = X[(size_t)row * 64 + lane];
    const float4 wr = *reinterpret_cast<const float4*>(W + lane * 4);
    float a0 = xv * wr.x, a1 = xv * wr.y, a2 = xv * wr.z, a3 = xv * wr.w;
#pragma unroll
    for (int off = 32; off; off >>= 1) {
        a0 += __shfl_xor(a0, off);
        a1 += __shfl_xor(a1, off);
        a2 += __shfl_xor(a2, off);
        a3 += __shfl_xor(a3, off);
    }
    if (lane == 0) {
        Y[(size_t)row * 4 + 0] = a0 + bias[0];
        Y[(size_t)row * 4 + 1] = a1 + bias[1];
        Y[(size_t)row * 4 + 2] = a2 + bias[2];
        Y[(size_t)row * 4 + 3] = a3 + bias[3];
    }
}

// ---------------------------------------------------------------------------
extern "C" void kernel_launch(void* const* d_in, const int* in_sizes, int n_in,
                              void* d_out, int out_size, void* d_ws, size_t ws_size,
                              hipStream_t stream)
{
    const float* x     = (const float*)d_in[0];
    const int*   ei    = (const int*)d_in[1];
    const int*   batch = (const int*)d_in[2];
    const float* W1  = (const float*)d_in[3];
    const float* b1  = (const float*)d_in[4];
    const float* g1  = (const float*)d_in[5];
    const float* be1 = (const float*)d_in[6];
    const float* W2  = (const float*)d_in[7];
    const float* b2  = (const float*)d_in[8];
    const float* g2  = (const float*)d_in[9];
    const float* be2 = (const float*)d_in[10];
    const float* Wg  = (const float*)d_in[11];
    const float* bg  = (const float*)d_in[12];
    const float* gg  = (const float*)d_in[13];
    const float* bgg = (const float*)d_in[14];
    const float* Wa1 = (const float*)d_in[15];
    const float* ba1 = (const float*)d_in[16];
    const float* Wa2 = (const float*)d_in[17];
    const float* ba2 = (const float*)d_in[18];
    const float* Wc1 = (const float*)d_in[19];
    const float* bc1 = (const float*)d_in[20];
    const float* gc1 = (const float*)d_in[21];
    const float* bec1= (const float*)d_in[22];
    const float* Wc2 = (const float*)d_in[23];
    const float* bc2 = (const float*)d_in[24];
    const float* gc2 = (const float*)d_in[25];
    const float* bec2= (const float*)d_in[26];
    const float* Wc3 = (const float*)d_in[27];
    const float* bc3 = (const float*)d_in[28];
    const float* gc3 = (const float*)d_in[29];
    const float* bec3= (const float*)d_in[30];
    const float* Wc4 = (const float*)d_in[31];
    const float* bc4 = (const float*)d_in[32];
    float* out = (float*)d_out;

    const int N = in_sizes[0] / 128;
    const int E = in_sizes[1] / 2;
    const int G = GGRAPHS;

    // workspace carve-up
    size_t off = 0;
    auto alloc = [&](size_t bytes) -> void* {
        void* p = (char*)d_ws + off;
        off += (bytes + 255) & ~(size_t)255;
        return p;
    };
    float*   hA     = (float*)alloc((size_t)N * 128 * 4);
    float*   hB     = (float*)alloc((size_t)N * 128 * 4);
    ushort4* hbf    = (ushort4*)alloc((size_t)N * 128 * 2);
    float*   aw     = (float*)alloc((size_t)N * 4);
    float*   dinv   = (float*)alloc((size_t)N * 4);
    int*     cnt    = (int*)alloc((size_t)N * 4);
    int*     rank   = (int*)alloc((size_t)E * 4);
    int*     rowptr = (int*)alloc((size_t)(N + 1) * 4);
    int*     bsum   = (int*)alloc(64 * 4);
    int2*    csr    = (int2*)alloc((size_t)E * 8);
    int*     bound  = (int*)alloc((size_t)(G + 1) * 4);
    float*   comb   = (float*)alloc((size_t)G * 512 * 4);
    float*   ps     = (float*)alloc((size_t)G * POOL_NC * 128 * 4);
    float*   pm     = (float*)alloc((size_t)G * POOL_NC * 128 * 4);
    float*   pw     = (float*)alloc((size_t)G * POOL_NC * 128 * 4);
    float*   z1     = (float*)alloc((size_t)G * 256 * 4);
    float*   z2     = (float*)alloc((size_t)G * 128 * 4);
    float*   z3     = (float*)alloc((size_t)G * 64 * 4);
    (void)ws_size;

    const int* e_src = ei;
    const int* e_dst = ei + E;

    // ---- CSR build over dst (reused by all 3 GCN layers) ----
    hipMemsetAsync(cnt, 0, (size_t)N * 4, stream);
    count_rank_kernel<<<(E + 255) / 256, 256, 0, stream>>>(e_dst, cnt, rank, E);
    const int nb = (N + 1023) / 1024;
    scan_local<<<nb, 1024, 0, stream>>>(cnt, rowptr, bsum, dinv, N);
    scan_bsum<<<1, 64, 0, stream>>>(bsum, nb);
    scan_add<<<nb, 1024, 0, stream>>>(rowptr, bsum, N);
    fill_kernel<<<(E + 255) / 256, 256, 0, stream>>>(e_src, e_dst, dinv, rowptr, rank, csr, E);

    const int rowblocks = (N + 127) / 128;   // 391

    // ---- input projection (ping-pong: col-split forbids in-place X==Y) ----
    gemm_fused<128, true, true, false, false, false><<<rowblocks * 2, 256, 0, stream>>>(
        x,  W1, b1, g1, be1, nullptr, hA, nullptr, nullptr, nullptr, nullptr, N);
    gemm_fused<128, true, true, false, false, true><<<rowblocks * 2, 256, 0, stream>>>(
        hA, W2, b2, g2, be2, nullptr, hB, hbf, nullptr, nullptr, nullptr, N);

    // ---- GCN layers: h lives in hB; agg -> hA; gemm X=hA, resid=Y=hB ----
    for (int l = 0; l < 3; ++l) {
        agg_kernel<<<(N + 7) / 8, 256, 0, stream>>>(hbf, csr, rowptr, dinv, hA, N);
        if (l < 2) {
            gemm_fused<128, true, true, true, false, true><<<rowblocks * 2, 256, 0, stream>>>(
                hA, Wg + (size_t)l * 128 * 128, bg + (size_t)l * 128,
                gg + (size_t)l * 128, bgg + (size_t)l * 128, hB, hB, hbf,
                nullptr, nullptr, nullptr, N);
        } else {
            gemm_fused<128, true, true, true, false, false><<<rowblocks * 2, 256, 0, stream>>>(
                hA, Wg + (size_t)l * 128 * 128, bg + (size_t)l * 128,
                gg + (size_t)l * 128, bgg + (size_t)l * 128, hB, hB, nullptr,
                nullptr, nullptr, nullptr, N);
        }
    }

    // ---- attention weights (fused: gelu(h@Wa1+ba1)@Wa2+ba2 -> tanh) ----
    gemm_fused<64, false, true, false, true, false><<<rowblocks, 256, 0, stream>>>(
        hB, Wa1, ba1, nullptr, nullptr, nullptr, nullptr, nullptr, Wa2, ba2, aw, N);

    // ---- pooling (h = hB) ----
    bounds_kernel<<<1, 256, 0, stream>>>(batch, bound, N, G);
    pool_partial<<<G * POOL_NC, 128, 0, stream>>>(hB, aw, bound, ps, pm, pw);
    pool_final<<<G, 128, 0, stream>>>(ps, pm, pw, bound, comb);

    // ---- classifier head ----
    rowgemm2<512, 256, true, true><<<G * 4, 256, 0, stream>>>(comb, Wc1, bc1, gc1, bec1, z1);
    rowgemm2<256, 128, true, true><<<G * 2, 256, 0, stream>>>(z1, Wc2, bc2, gc2, bec2, z2);
    rowgemm2<128, 64,  true, true><<<G * 1, 256, 0, stream>>>(z2, Wc3, bc3, gc3, bec3, z3);
    rowgemm_final<<<G, 64, 0, stream>>>(z3, Wc4, bc4, out);
}

// Round 9
// 413.943 us; speedup vs baseline: 5.5276x; 1.3165x over previous
//
#include <hip/hip_runtime.h>
#include <hip/hip_bf16.h>
#include <float.h>

// ---------------------------------------------------------------------------
// ImprovedTransformerGNN: bf16-MFMA GEMMs + bf16 gather agg, fp32 epilogues.
// N=50000, E=600000, H=128, IN=128, C=4, L=3, G=128.
// R9: fp32 vector GEMM plateaued at ~43us (3 shapes tried; FMA floor 10.4us,
//     issue mix caps VALUBusy ~35%). Switch the 6 N-row GEMMs to
//     mfma_f32_16x16x32_bf16: A-frags direct-from-global bf16 rows
//     (8 contiguous k/lane), W^T bf16 staged to LDS with XOR swizzle
//     (byte ^= (row&7)<<4, G4), C/D layout col=lane&15 row=(lane>>4)*4+rid.
//     agg emits bf16 directly. Residual/pooling stay fp32.
// ---------------------------------------------------------------------------

#define GGRAPHS 128
#define POOL_NC 16

typedef __attribute__((ext_vector_type(8))) short short8b;  // 8 bf16 = 4 VGPR
typedef __attribute__((ext_vector_type(4))) float f32x4;

__device__ __forceinline__ float gelu_f(float x) {
    return 0.5f * x * (1.0f + erff(x * 0.7071067811865476f));
}

__device__ __forceinline__ unsigned short f2bf(float f) {  // RNE, finite inputs
    unsigned int u = __float_as_uint(f);
    unsigned int r = (u + 0x7FFFu + ((u >> 16) & 1u)) >> 16;
    return (unsigned short)r;
}

__device__ __forceinline__ float bf2f(unsigned short u) {
    return __uint_as_float(((unsigned int)u) << 16);
}

static constexpr float BNS_F = 0.99999500003749968f;  // 1/sqrt(1+1e-5)

// ---------------------------------------------------------------------------
// preprocessing: fp32 -> bf16 (x), and W[K][M] -> W^T bf16 [M][K] (K=128)
// ---------------------------------------------------------------------------
__global__ void tobf_kernel(const float4* __restrict__ X, ushort4* __restrict__ Xb, int n4)
{
    int id = blockIdx.x * 256 + threadIdx.x;
    if (id < n4) {
        float4 v = X[id];
        ushort4 q;
        q.x = f2bf(v.x); q.y = f2bf(v.y); q.z = f2bf(v.z); q.w = f2bf(v.w);
        Xb[id] = q;
    }
}

__global__ void transpose_bf_kernel(const float* __restrict__ W, unsigned short* __restrict__ Wt,
                                    int K, int M)
{
    int id = blockIdx.x * 256 + threadIdx.x;
    if (id < K * M) {
        int k = id / M, c = id % M;
        Wt[c * K + k] = f2bf(W[id]);
    }
}

// ---------------------------------------------------------------------------
// MFMA GEMM: Y[nrows,M] = act( (A[nrows,128] @ W[128,M]) * sc + bi ) (+resid)
// A bf16 row-major [nrows][128]; Wtb = W^T bf16 [M][128].
// Block 256 = 4 waves; tile 64 rows x M cols; wave w owns rows [w*16,+16).
// Per wave: NCT=M/16 col-tiles x 4 k-steps MFMAs. A-frag from GLOBAL
// (lane: row=rb+(l&15), k=(l>>4)*8.., 16B), reused across col-tiles.
// B-frag from swizzled LDS W^T (lane: col=ct*16+(l&15), same k block).
// C/D: col=lane&15, row=(lane>>4)*4+rid (m89/m91-verified).
// DO_AW (M=64): aw[r]=tanh(gelu(row)@Wa2+ba2) instead of Y.
// ---------------------------------------------------------------------------
template<int M, bool DO_BN, bool DO_GELU, bool DO_RES, bool DO_AW, bool DO_F32, bool DO_BF16>
__global__ __launch_bounds__(256, 2)
void gemm_mfma(const unsigned short* __restrict__ Abf,
               const unsigned short* __restrict__ Wtb,
               const float* __restrict__ bias, const float* __restrict__ gam,
               const float* __restrict__ beta, const float* __restrict__ resid,
               float* __restrict__ Yf, unsigned short* __restrict__ Ybf,
               const float* __restrict__ Wa2, const float* __restrict__ ba2,
               float* __restrict__ awout, int nrows)
{
    constexpr int NCT = M / 16;
    __shared__ unsigned short Wl[M * 128];   // 32KB (M=128) / 16KB (M=64)

    const int tid = threadIdx.x;

    // stage W^T into LDS, XOR-swizzled (row = W^T row = output col)
    constexpr int NCH = M * 16;   // 16B chunks
#pragma unroll
    for (int i = 0; i < NCH / 256; ++i) {
        const int idx = i * 256 + tid;
        const uint4 v = reinterpret_cast<const uint4*>(Wtb)[idx];
        const int byte = idx * 16;
        const int swz = byte ^ (((byte >> 8) & 7) << 4);
        *reinterpret_cast<uint4*>(reinterpret_cast<char*>(Wl) + swz) = v;
    }
    __syncthreads();

    const int w = tid >> 6;
    const int l = tid & 63;
    const int l4 = l >> 4, lm = l & 15;
    const int rowbase = (int)blockIdx.x * 64 + w * 16;

    // A fragments for all 4 k-steps, direct from global
    int arow = rowbase + lm; if (arow >= nrows) arow = nrows - 1;
    const unsigned short* ap = Abf + (size_t)arow * 128 + l4 * 8;
    short8b a[4];
#pragma unroll
    for (int ks = 0; ks < 4; ++ks)
        a[ks] = *reinterpret_cast<const short8b*>(ap + ks * 32);

    f32x4 acc[NCT];
#pragma unroll
    for (int ct = 0; ct < NCT; ++ct) acc[ct] = f32x4{0.f, 0.f, 0.f, 0.f};

    const int swzm = (lm & 7) << 4;
    const char* Wlc = reinterpret_cast<const char*>(Wl);
#pragma unroll
    for (int ks = 0; ks < 4; ++ks) {
#pragma unroll
        for (int ct = 0; ct < NCT; ++ct) {
            const int byte = ct * 4096 + lm * 256 + ks * 64 + l4 * 16;
            const short8b bv = *reinterpret_cast<const short8b*>(Wlc + (byte ^ swzm));
            acc[ct] = __builtin_amdgcn_mfma_f32_16x16x32_bf16(a[ks], bv, acc[ct], 0, 0, 0);
        }
    }

    if (DO_AW) {
        // M=64: per lane, col = ct*16+lm fixed per ct; rows = rowbase+l4*4+rid
        float p[4] = {0.f, 0.f, 0.f, 0.f};
#pragma unroll
        for (int ct = 0; ct < NCT; ++ct) {
            const int col = ct * 16 + lm;
            float sc, bi;
            if (DO_BN) { float g = gam[col]; sc = g * BNS_F; bi = bias[col] * sc + beta[col]; }
            else       { sc = 1.f; bi = bias[col]; }
            const float wa = Wa2[col];
#pragma unroll
            for (int rid = 0; rid < 4; ++rid) {
                float v = acc[ct][rid] * sc + bi;
                if (DO_GELU) v = gelu_f(v);
                p[rid] = fmaf(v, wa, p[rid]);
            }
        }
        const float ba2v = ba2[0];
#pragma unroll
        for (int rid = 0; rid < 4; ++rid) {
            float v = p[rid];
            v += __shfl_xor(v, 1);
            v += __shfl_xor(v, 2);
            v += __shfl_xor(v, 4);
            v += __shfl_xor(v, 8);
            const int row = rowbase + l4 * 4 + rid;
            if (lm == 0 && row < nrows) awout[row] = tanhf(v + ba2v);
        }
        return;
    }

#pragma unroll
    for (int ct = 0; ct < NCT; ++ct) {
        const int col = ct * 16 + lm;
        float sc, bi;
        if (DO_BN) { float g = gam[col]; sc = g * BNS_F; bi = bias[col] * sc + beta[col]; }
        else       { sc = 1.f; bi = bias[col]; }
#pragma unroll
        for (int rid = 0; rid < 4; ++rid) {
            const int row = rowbase + l4 * 4 + rid;
            if (row < nrows) {
                float v = acc[ct][rid] * sc + bi;
                if (DO_GELU) v = gelu_f(v);
                if (DO_RES) v += resid[(size_t)row * M + col];
                if (DO_F32) Yf[(size_t)row * M + col] = v;
                if (DO_BF16) Ybf[(size_t)row * M + col] = f2bf(v);
            }
        }
    }
}

// ---------------------------------------------------------------------------
// CSR build: count + per-edge rank (atomic), scan (+dinv), atomic-free fill.
// ---------------------------------------------------------------------------
__global__ void count_rank_kernel(const int* __restrict__ dst, int* __restrict__ cnt,
                                  int* __restrict__ rank, int E)
{
    int e = blockIdx.x * 256 + threadIdx.x;
    if (e < E) rank[e] = atomicAdd(&cnt[dst[e]], 1);
}

__global__ void scan_local(const int* __restrict__ cnt, int* __restrict__ rowptr,
                           int* __restrict__ bsum, float* __restrict__ dinv, int n)
{
    __shared__ int sd[1024];
    const int tid = threadIdx.x;
    const int i = blockIdx.x * 1024 + tid;
    int v = (i < n) ? cnt[i] : 0;
    if (i < n) dinv[i] = rsqrtf((float)v + 1.0f);
    sd[tid] = v;
    __syncthreads();
    for (int off = 1; off < 1024; off <<= 1) {
        int t = (tid >= off) ? sd[tid - off] : 0;
        __syncthreads();
        sd[tid] += t;
        __syncthreads();
    }
    if (i < n) rowptr[i + 1] = sd[tid];
    if (tid == 1023) bsum[blockIdx.x] = sd[1023];
}

__global__ void scan_bsum(int* __restrict__ bsum, int nb)
{
    const int lane = threadIdx.x;  // 64 threads, nb <= 64
    int orig = (lane < nb) ? bsum[lane] : 0;
    int v = orig;
#pragma unroll
    for (int off = 1; off < 64; off <<= 1) {
        int t = __shfl_up(v, off);
        if (lane >= off) v += t;
    }
    if (lane < nb) bsum[lane] = v - orig;  // exclusive prefix
}

__global__ void scan_add(int* __restrict__ rowptr, const int* __restrict__ bsum, int n)
{
    const int i = blockIdx.x * 1024 + threadIdx.x;
    if (i < n) rowptr[i + 1] += bsum[blockIdx.x];
    if (i == 0) rowptr[0] = 0;
}

__global__ void fill_kernel(const int* __restrict__ src, const int* __restrict__ dst,
                            const float* __restrict__ dinv, const int* __restrict__ rowptr,
                            const int* __restrict__ rank, int2* __restrict__ csr, int E)
{
    int e = blockIdx.x * 256 + threadIdx.x;
    if (e < E) {
        const int d = dst[e], s = src[e];
        const int pos = rowptr[d] + rank[e];
        int2 p;
        p.x = s;
        p.y = __float_as_int(dinv[s] * dinv[d]);
        csr[pos] = p;
    }
}

// ---------------------------------------------------------------------------
// Aggregation (gather over CSR, bf16 rows): ah = h*snorm + sum h[src]*w
// 32 threads/node (ushort4 lanes = 8B), 8 nodes/block, 4-edge unroll.
// fp32 accumulate, bf16 output (feeds MFMA A directly).
// ---------------------------------------------------------------------------
#define FMAB(A, Wt, U) { A.x = fmaf(Wt, bf2f(U.x), A.x); A.y = fmaf(Wt, bf2f(U.y), A.y); \
                         A.z = fmaf(Wt, bf2f(U.z), A.z); A.w = fmaf(Wt, bf2f(U.w), A.w); }

__global__ __launch_bounds__(256)
void agg_kernel(const ushort4* __restrict__ hb, const int2* __restrict__ csr,
                const int* __restrict__ rowptr, const float* __restrict__ dinv,
                ushort4* __restrict__ ahb, int n)
{
    const int node = blockIdx.x * 8 + (threadIdx.x >> 5);
    if (node >= n) return;
    const int lane = threadIdx.x & 31;  // ushort4 index within the 128-wide row

    const float di = dinv[node];
    const float sw = di * di;
    const ushort4 sv = hb[(size_t)node * 32 + lane];
    float4 a0, a1;
    a0.x = bf2f(sv.x) * sw; a0.y = bf2f(sv.y) * sw;
    a0.z = bf2f(sv.z) * sw; a0.w = bf2f(sv.w) * sw;
    a1.x = 0.f; a1.y = 0.f; a1.z = 0.f; a1.w = 0.f;

    const int beg = rowptr[node], end = rowptr[node + 1];
    int s = beg;
    for (; s + 4 <= end; s += 4) {
        const int2 e0 = csr[s+0], e1 = csr[s+1], e2 = csr[s+2], e3 = csr[s+3];
        const ushort4 v0 = hb[(size_t)e0.x * 32 + lane];
        const ushort4 v1 = hb[(size_t)e1.x * 32 + lane];
        const ushort4 v2 = hb[(size_t)e2.x * 32 + lane];
        const ushort4 v3 = hb[(size_t)e3.x * 32 + lane];
        FMAB(a0, __int_as_float(e0.y), v0); FMAB(a1, __int_as_float(e1.y), v1);
        FMAB(a0, __int_as_float(e2.y), v2); FMAB(a1, __int_as_float(e3.y), v3);
    }
    for (; s < end; ++s) {
        const int2 e0 = csr[s];
        const ushort4 v = hb[(size_t)e0.x * 32 + lane];
        FMAB(a0, __int_as_float(e0.y), v);
    }
    ushort4 q;
    q.x = f2bf(a0.x + a1.x); q.y = f2bf(a0.y + a1.y);
    q.z = f2bf(a0.z + a1.z); q.w = f2bf(a0.w + a1.w);
    ahb[(size_t)node * 32 + lane] = q;
}

// ---------------------------------------------------------------------------
// batch is sorted: per-graph boundaries via binary search
// ---------------------------------------------------------------------------
__global__ void bounds_kernel(const int* __restrict__ batch, int* __restrict__ bound, int n, int g)
{
    const int t = blockIdx.x * blockDim.x + threadIdx.x;
    if (t > g) return;
    int lo = 0, hi = n;
    while (lo < hi) { int mid = (lo + hi) >> 1; if (batch[mid] < t) lo = mid + 1; else hi = mid; }
    bound[t] = lo;
}

// ---------------------------------------------------------------------------
// 2-stage deterministic pooling. Stage 1: 16 fixed chunks per graph.
// ---------------------------------------------------------------------------
__global__ void pool_partial(const float* __restrict__ h, const float* __restrict__ aw,
                             const int* __restrict__ bound, float* __restrict__ ps,
                             float* __restrict__ pm, float* __restrict__ pw)
{
    const int g = blockIdx.x >> 4;
    const int c = blockIdx.x & (POOL_NC - 1);
    const int f = threadIdx.x;  // 128 threads
    const int beg = bound[g], end = bound[g + 1];
    const int len = end - beg;
    const int cbeg = beg + (int)(((long long)len * c) / POOL_NC);
    const int cend = beg + (int)(((long long)len * (c + 1)) / POOL_NC);
    float s = 0.f, m = -FLT_MAX, w = 0.f;
    for (int node = cbeg; node < cend; ++node) {
        const float v = h[(size_t)node * 128 + f];
        const float a = aw[node];
        s += v;
        m = fmaxf(m, v);
        w = fmaf(v, a, w);
    }
    const size_t idx = ((size_t)g * POOL_NC + c) * 128 + f;
    ps[idx] = s; pm[idx] = m; pw[idx] = w;
}

__global__ void pool_final(const float* __restrict__ ps, const float* __restrict__ pm,
                           const float* __restrict__ pw, const int* __restrict__ bound,
                           float* __restrict__ comb)
{
    const int g = blockIdx.x;
    const int f = threadIdx.x;  // 128 threads
    float s = 0.f, m = -FLT_MAX, w = 0.f;
#pragma unroll
    for (int c = 0; c < POOL_NC; ++c) {
        const size_t idx = ((size_t)g * POOL_NC + c) * 128 + f;
        s += ps[idx];
        m = fmaxf(m, pm[idx]);
        w += pw[idx];
    }
    float cn = (float)(bound[g + 1] - bound[g]);
    if (cn < 1.f) cn = 1.f;
    comb[(size_t)g * 512 + f]       = s / cn;
    comb[(size_t)g * 512 + 128 + f] = m;
    comb[(size_t)g * 512 + 256 + f] = s / cn;
    comb[(size_t)g * 512 + 384 + f] = w / cn;
}

// ---------------------------------------------------------------------------
// classifier head GEMM: grid = G * (M/64); block 256 = 64 cols x 4 k-quarters.
// ---------------------------------------------------------------------------
template<int K, int M, bool DO_BN, bool DO_GELU>
__global__ __launch_bounds__(256)
void rowgemm2(const float* __restrict__ X, const float* __restrict__ W,
              const float* __restrict__ bias, const float* __restrict__ gam,
              const float* __restrict__ beta, float* __restrict__ Y)
{
    constexpr int NC = M / 64;
    constexpr int KQ = K / 4;
    const int row = blockIdx.x / NC;
    const int lane = threadIdx.x & 63;
    const int c = (blockIdx.x % NC) * 64 + lane;
    const int q = threadIdx.x >> 6;  // k-quarter 0..3

    const float* __restrict__ xq = X + (size_t)row * K + q * KQ;
    const float* __restrict__ wq = W + (size_t)(q * KQ) * M + c;

    float a0 = 0.f, a1 = 0.f, a2 = 0.f, a3 = 0.f;
#pragma unroll 4
    for (int k = 0; k < KQ; k += 4) {
        const float4 xv = *reinterpret_cast<const float4*>(xq + k);
        a0 = fmaf(xv.x, wq[(size_t)(k + 0) * M], a0);
        a1 = fmaf(xv.y, wq[(size_t)(k + 1) * M], a1);
        a2 = fmaf(xv.z, wq[(size_t)(k + 2) * M], a2);
        a3 = fmaf(xv.w, wq[(size_t)(k + 3) * M], a3);
    }
    __shared__ float part[4][64];
    part[q][lane] = (a0 + a1) + (a2 + a3);
    __syncthreads();
    if (q == 0) {
        float v = (part[0][lane] + part[1][lane]) + (part[2][lane] + part[3][lane]);
        if (DO_BN) { const float g = gam[c]; const float sc = g * BNS_F; v = v * sc + (bias[c] * sc + beta[c]); }
        else       { v = v + bias[c]; }
        if (DO_GELU) v = gelu_f(v);
        Y[(size_t)row * M + c] = v;
    }
}

// final layer: [G,64] @ [64,4] + bias; one wave per row, shuffle reduce
__global__ void rowgemm_final(const float* __restrict__ X, const float* __restrict__ W,
                              const float* __restrict__ bias, float* __restrict__ Y)
{
    const int row = blockIdx.x;
    const int lane = threadIdx.x;  // 64
    const float xv = X[(size_t)row * 64 + lane];
    const float4 wr = *reinterpret_cast<const float4*>(W + lane * 4);
    float a0 = xv * wr.x, a1 = xv * wr.y, a2 = xv * wr.z, a3 = xv * wr.w;
#pragma unroll
    for (int off = 32; off; off >>= 1) {
        a0 += __shfl_xor(a0, off);
        a1 += __shfl_xor(a1, off);
        a2 += __shfl_xor(a2, off);
        a3 += __shfl_xor(a3, off);
    }
    if (lane == 0) {
        Y[(size_t)row * 4 + 0] = a0 + bias[0];
        Y[(size_t)row * 4 + 1] = a1 + bias[1];
        Y[(size_t)row * 4 + 2] = a2 + bias[2];
        Y[(size_t)row * 4 + 3] = a3 + bias[3];
    }
}

// ---------------------------------------------------------------------------
extern "C" void kernel_launch(void* const* d_in, const int* in_sizes, int n_in,
                              void* d_out, int out_size, void* d_ws, size_t ws_size,
                              hipStream_t stream)
{
    const float* x     = (const float*)d_in[0];
    const int*   ei    = (const int*)d_in[1];
    const int*   batch = (const int*)d_in[2];
    const float* W1  = (const float*)d_in[3];
    const float* b1  = (const float*)d_in[4];
    const float* g1  = (const float*)d_in[5];
    const float* be1 = (const float*)d_in[6];
    const float* W2  = (const float*)d_in[7];
    const float* b2  = (const float*)d_in[8];
    const float* g2  = (const float*)d_in[9];
    const float* be2 = (const float*)d_in[10];
    const float* Wg  = (const float*)d_in[11];
    const float* bg  = (const float*)d_in[12];
    const float* gg  = (const float*)d_in[13];
    const float* bgg = (const float*)d_in[14];
    const float* Wa1 = (const float*)d_in[15];
    const float* ba1 = (const float*)d_in[16];
    const float* Wa2 = (const float*)d_in[17];
    const float* ba2 = (const float*)d_in[18];
    const float* Wc1 = (const float*)d_in[19];
    const float* bc1 = (const float*)d_in[20];
    const float* gc1 = (const float*)d_in[21];
    const float* bec1= (const float*)d_in[22];
    const float* Wc2 = (const float*)d_in[23];
    const float* bc2 = (const float*)d_in[24];
    const float* gc2 = (const float*)d_in[25];
    const float* bec2= (const float*)d_in[26];
    const float* Wc3 = (const float*)d_in[27];
    const float* bc3 = (const float*)d_in[28];
    const float* gc3 = (const float*)d_in[29];
    const float* bec3= (const float*)d_in[30];
    const float* Wc4 = (const float*)d_in[31];
    const float* bc4 = (const float*)d_in[32];
    float* out = (float*)d_out;

    const int N = in_sizes[0] / 128;
    const int E = in_sizes[1] / 2;
    const int G = GGRAPHS;

    // workspace carve-up
    size_t off = 0;
    auto alloc = [&](size_t bytes) -> void* {
        void* p = (char*)d_ws + off;
        off += (bytes + 255) & ~(size_t)255;
        return p;
    };
    float*          hB    = (float*)alloc((size_t)N * 128 * 4);           // fp32 h (resid/pool)
    unsigned short* xb    = (unsigned short*)alloc((size_t)N * 128 * 2);  // bf16 x
    unsigned short* hAb   = (unsigned short*)alloc((size_t)N * 128 * 2);  // bf16 proj1 out
    unsigned short* hbf   = (unsigned short*)alloc((size_t)N * 128 * 2);  // bf16 h (gather/A)
    unsigned short* ahb   = (unsigned short*)alloc((size_t)N * 128 * 2);  // bf16 agg out
    unsigned short* Wt1   = (unsigned short*)alloc(128 * 128 * 2);
    unsigned short* Wt2   = (unsigned short*)alloc(128 * 128 * 2);
    unsigned short* Wtg   = (unsigned short*)alloc(3 * 128 * 128 * 2);
    unsigned short* Wta1  = (unsigned short*)alloc(64 * 128 * 2);
    float*   aw     = (float*)alloc((size_t)N * 4);
    float*   dinv   = (float*)alloc((size_t)N * 4);
    int*     cnt    = (int*)alloc((size_t)N * 4);
    int*     rank   = (int*)alloc((size_t)E * 4);
    int*     rowptr = (int*)alloc((size_t)(N + 1) * 4);
    int*     bsum   = (int*)alloc(64 * 4);
    int2*    csr    = (int2*)alloc((size_t)E * 8);
    int*     bound  = (int*)alloc((size_t)(G + 1) * 4);
    float*   comb   = (float*)alloc((size_t)G * 512 * 4);
    float*   ps     = (float*)alloc((size_t)G * POOL_NC * 128 * 4);
    float*   pm     = (float*)alloc((size_t)G * POOL_NC * 128 * 4);
    float*   pw     = (float*)alloc((size_t)G * POOL_NC * 128 * 4);
    float*   z1     = (float*)alloc((size_t)G * 256 * 4);
    float*   z2     = (float*)alloc((size_t)G * 128 * 4);
    float*   z3     = (float*)alloc((size_t)G * 64 * 4);
    (void)ws_size;

    const int* e_src = ei;
    const int* e_dst = ei + E;

    // ---- preprocessing: bf16 conversions (x) and weight transposes ----
    tobf_kernel<<<(N * 32 + 255) / 256, 256, 0, stream>>>(
        (const float4*)x, (ushort4*)xb, N * 32);
    transpose_bf_kernel<<<64, 256, 0, stream>>>(W1, Wt1, 128, 128);
    transpose_bf_kernel<<<64, 256, 0, stream>>>(W2, Wt2, 128, 128);
    for (int l = 0; l < 3; ++l)
        transpose_bf_kernel<<<64, 256, 0, stream>>>(Wg + (size_t)l * 16384, Wtg + (size_t)l * 16384, 128, 128);
    transpose_bf_kernel<<<32, 256, 0, stream>>>(Wa1, Wta1, 128, 64);

    // ---- CSR build over dst (reused by all 3 GCN layers) ----
    hipMemsetAsync(cnt, 0, (size_t)N * 4, stream);
    count_rank_kernel<<<(E + 255) / 256, 256, 0, stream>>>(e_dst, cnt, rank, E);
    const int nb = (N + 1023) / 1024;
    scan_local<<<nb, 1024, 0, stream>>>(cnt, rowptr, bsum, dinv, N);
    scan_bsum<<<1, 64, 0, stream>>>(bsum, nb);
    scan_add<<<nb, 1024, 0, stream>>>(rowptr, bsum, N);
    fill_kernel<<<(E + 255) / 256, 256, 0, stream>>>(e_src, e_dst, dinv, rowptr, rank, csr, E);

    const int rowblocks = (N + 63) / 64;   // 782

    // ---- input projection ----
    gemm_mfma<128, true, true, false, false, false, true><<<rowblocks, 256, 0, stream>>>(
        xb, Wt1, b1, g1, be1, nullptr, nullptr, hAb, nullptr, nullptr, nullptr, N);
    gemm_mfma<128, true, true, false, false, true, true><<<rowblocks, 256, 0, stream>>>(
        hAb, Wt2, b2, g2, be2, nullptr, hB, hbf, nullptr, nullptr, nullptr, N);

    // ---- GCN layers: agg (bf16) -> MFMA gemm (resid fp32) ----
    for (int l = 0; l < 3; ++l) {
        agg_kernel<<<(N + 7) / 8, 256, 0, stream>>>(
            (const ushort4*)hbf, csr, rowptr, dinv, (ushort4*)ahb, N);
        gemm_mfma<128, true, true, true, false, true, true><<<rowblocks, 256, 0, stream>>>(
            ahb, Wtg + (size_t)l * 16384, bg + (size_t)l * 128,
            gg + (size_t)l * 128, bgg + (size_t)l * 128, hB, hB, hbf,
            nullptr, nullptr, nullptr, N);
    }

    // ---- attention weights (fused: gelu(h@Wa1+ba1)@Wa2+ba2 -> tanh) ----
    gemm_mfma<64, false, true, false, true, false, false><<<rowblocks, 256, 0, stream>>>(
        hbf, Wta1, ba1, nullptr, nullptr, nullptr, nullptr, nullptr, Wa2, ba2, aw, N);

    // ---- pooling (h = hB fp32) ----
    bounds_kernel<<<1, 256, 0, stream>>>(batch, bound, N, G);
    pool_partial<<<G * POOL_NC, 128, 0, stream>>>(hB, aw, bound, ps, pm, pw);
    pool_final<<<G, 128, 0, stream>>>(ps, pm, pw, bound, comb);

    // ---- classifier head (fp32, tiny) ----
    rowgemm2<512, 256, true, true><<<G * 4, 256, 0, stream>>>(comb, Wc1, bc1, gc1, bec1, z1);
    rowgemm2<256, 128, true, true><<<G * 2, 256, 0, stream>>>(z1, Wc2, bc2, gc2, bec2, z2);
    rowgemm2<128, 64,  true, true><<<G * 1, 256, 0, stream>>>(z2, Wc3, bc3, gc3, bec3, z3);
    rowgemm_final<<<G, 64, 0, stream>>>(z3, Wc4, bc4, out);
}

// Round 10
// 382.575 us; speedup vs baseline: 5.9808x; 1.0820x over previous
//
#include <hip/hip_runtime.h>
#include <hip/hip_bf16.h>
#include <float.h>

// ---------------------------------------------------------------------------
// ImprovedTransformerGNN: bf16-MFMA GEMMs, bf16-resident h, fp32 accum.
// N=50000, E=600000, H=128, IN=128, C=4, L=3, G=128.
// R10: (1) h lives ONLY in bf16 (residual read + in-place write bf16, pool
//      reads bf16) -- kills the dual fp32/bf16 h streams (~150 MB);
//      (2) fp32->bf16 conversion fused into proj1 (A_FP32 flag);
//      (3) 6 transpose launches merged to 1; bounds search inlined into pool.
//      29 -> 22 dispatches.
// ---------------------------------------------------------------------------

#define GGRAPHS 128
#define POOL_NC 16

typedef __attribute__((ext_vector_type(8))) short short8b;  // 8 bf16 = 4 VGPR
typedef __attribute__((ext_vector_type(4))) float f32x4;

__device__ __forceinline__ float gelu_f(float x) {
    return 0.5f * x * (1.0f + erff(x * 0.7071067811865476f));
}

__device__ __forceinline__ unsigned short f2bf(float f) {  // RNE, finite inputs
    unsigned int u = __float_as_uint(f);
    unsigned int r = (u + 0x7FFFu + ((u >> 16) & 1u)) >> 16;
    return (unsigned short)r;
}

__device__ __forceinline__ float bf2f(unsigned short u) {
    return __uint_as_float(((unsigned int)u) << 16);
}

static constexpr float BNS_F = 0.99999500003749968f;  // 1/sqrt(1+1e-5)

// ---------------------------------------------------------------------------
// one-shot weight prep: 5x [128][128] + 1x [128][64] fp32 W -> bf16 W^T [M][K]
// ---------------------------------------------------------------------------
__global__ void transpose_all_kernel(const float* __restrict__ W1, const float* __restrict__ W2,
                                     const float* __restrict__ Wg, const float* __restrict__ Wa1,
                                     unsigned short* __restrict__ Wt1, unsigned short* __restrict__ Wt2,
                                     unsigned short* __restrict__ Wtg, unsigned short* __restrict__ Wta1)
{
    const int id = blockIdx.x * 256 + threadIdx.x;
    if (id < 81920) {
        const int m = id >> 14;           // 0:W1 1:W2 2..4:Wg[l]
        const int r = id & 16383;
        const int k = r >> 7, c = r & 127;
        const float* Wsrc = (m == 0) ? W1 : (m == 1) ? W2 : Wg + (size_t)(m - 2) * 16384;
        unsigned short* Wdst = (m == 0) ? Wt1 : (m == 1) ? Wt2 : Wtg + (size_t)(m - 2) * 16384;
        Wdst[c * 128 + k] = f2bf(Wsrc[r]);
    } else if (id < 90112) {
        const int r = id - 81920;         // Wa1 [128][64]
        const int k = r >> 6, c = r & 63;
        Wta1[c * 128 + k] = f2bf(Wa1[r]);
    }
}

// ---------------------------------------------------------------------------
// MFMA GEMM: Ybf[nrows,M] = bf16( act((A @ W)*sc + bi) (+ bf16 resid) )
// A: bf16 [nrows][128] (or fp32 if A_FP32, converted in-reg).
// Wtb: W^T bf16 [M][128], staged to LDS XOR-swizzled (byte ^= (row&7)<<4).
// Block 256 = 4 waves; tile 64 rows x M cols; wave w rows [w*16,+16).
// A-frag direct from global (lane: row=rb+(l&15), k=(l>>4)*8 in each 32-k).
// C/D: col=lane&15, row=(lane>>4)*4+rid. resid may alias Ybf (1:1
// thread<->element, read-before-write). DO_AW (M=64): emit aw instead.
// ---------------------------------------------------------------------------
template<int M, bool A_FP32, bool DO_BN, bool DO_GELU, bool DO_RES, bool DO_AW>
__global__ __launch_bounds__(256, 2)
void gemm_mfma(const void* __restrict__ Ain,
               const unsigned short* __restrict__ Wtb,
               const float* __restrict__ bias, const float* __restrict__ gam,
               const float* __restrict__ beta, const unsigned short* __restrict__ residb,
               unsigned short* __restrict__ Ybf,
               const float* __restrict__ Wa2, const float* __restrict__ ba2,
               float* __restrict__ awout, int nrows)
{
    constexpr int NCT = M / 16;
    __shared__ unsigned short Wl[M * 128];   // 32KB (M=128) / 16KB (M=64)

    const int tid = threadIdx.x;

    // stage W^T into LDS, XOR-swizzled (row = output col)
    constexpr int NCH = M * 16;   // 16B chunks
#pragma unroll
    for (int i = 0; i < NCH / 256; ++i) {
        const int idx = i * 256 + tid;
        const uint4 v = reinterpret_cast<const uint4*>(Wtb)[idx];
        const int byte = idx * 16;
        const int swz = byte ^ (((byte >> 8) & 7) << 4);
        *reinterpret_cast<uint4*>(reinterpret_cast<char*>(Wl) + swz) = v;
    }
    __syncthreads();

    const int w = tid >> 6;
    const int l = tid & 63;
    const int l4 = l >> 4, lm = l & 15;
    const int rowbase = (int)blockIdx.x * 64 + w * 16;

    // A fragments for all 4 k-steps, direct from global
    int arow = rowbase + lm; if (arow >= nrows) arow = nrows - 1;
    short8b a[4];
    if constexpr (A_FP32) {
        const float* apf = (const float*)Ain + (size_t)arow * 128 + l4 * 8;
#pragma unroll
        for (int ks = 0; ks < 4; ++ks) {
            const float4 v0 = *reinterpret_cast<const float4*>(apf + ks * 32);
            const float4 v1 = *reinterpret_cast<const float4*>(apf + ks * 32 + 4);
            short8b av;
            av[0] = (short)f2bf(v0.x); av[1] = (short)f2bf(v0.y);
            av[2] = (short)f2bf(v0.z); av[3] = (short)f2bf(v0.w);
            av[4] = (short)f2bf(v1.x); av[5] = (short)f2bf(v1.y);
            av[6] = (short)f2bf(v1.z); av[7] = (short)f2bf(v1.w);
            a[ks] = av;
        }
    } else {
        const unsigned short* ap = (const unsigned short*)Ain + (size_t)arow * 128 + l4 * 8;
#pragma unroll
        for (int ks = 0; ks < 4; ++ks)
            a[ks] = *reinterpret_cast<const short8b*>(ap + ks * 32);
    }

    f32x4 acc[NCT];
#pragma unroll
    for (int ct = 0; ct < NCT; ++ct) acc[ct] = f32x4{0.f, 0.f, 0.f, 0.f};

    const int swzm = (lm & 7) << 4;
    const char* Wlc = reinterpret_cast<const char*>(Wl);
#pragma unroll
    for (int ks = 0; ks < 4; ++ks) {
#pragma unroll
        for (int ct = 0; ct < NCT; ++ct) {
            const int byte = ct * 4096 + lm * 256 + ks * 64 + l4 * 16;
            const short8b bv = *reinterpret_cast<const short8b*>(Wlc + (byte ^ swzm));
            acc[ct] = __builtin_amdgcn_mfma_f32_16x16x32_bf16(a[ks], bv, acc[ct], 0, 0, 0);
        }
    }

    if (DO_AW) {
        float p[4] = {0.f, 0.f, 0.f, 0.f};
#pragma unroll
        for (int ct = 0; ct < NCT; ++ct) {
            const int col = ct * 16 + lm;
            float sc, bi;
            if (DO_BN) { float g = gam[col]; sc = g * BNS_F; bi = bias[col] * sc + beta[col]; }
            else       { sc = 1.f; bi = bias[col]; }
            const float wa = Wa2[col];
#pragma unroll
            for (int rid = 0; rid < 4; ++rid) {
                float v = acc[ct][rid] * sc + bi;
                if (DO_GELU) v = gelu_f(v);
                p[rid] = fmaf(v, wa, p[rid]);
            }
        }
        const float ba2v = ba2[0];
#pragma unroll
        for (int rid = 0; rid < 4; ++rid) {
            float v = p[rid];
            v += __shfl_xor(v, 1);
            v += __shfl_xor(v, 2);
            v += __shfl_xor(v, 4);
            v += __shfl_xor(v, 8);
            const int row = rowbase + l4 * 4 + rid;
            if (lm == 0 && row < nrows) awout[row] = tanhf(v + ba2v);
        }
        return;
    }

#pragma unroll
    for (int ct = 0; ct < NCT; ++ct) {
        const int col = ct * 16 + lm;
        float sc, bi;
        if (DO_BN) { float g = gam[col]; sc = g * BNS_F; bi = bias[col] * sc + beta[col]; }
        else       { sc = 1.f; bi = bias[col]; }
#pragma unroll
        for (int rid = 0; rid < 4; ++rid) {
            const int row = rowbase + l4 * 4 + rid;
            if (row < nrows) {
                float v = acc[ct][rid] * sc + bi;
                if (DO_GELU) v = gelu_f(v);
                if (DO_RES) v += bf2f(residb[(size_t)row * M + col]);
                Ybf[(size_t)row * M + col] = f2bf(v);
            }
        }
    }
}

// ---------------------------------------------------------------------------
// CSR build: count + per-edge rank (atomic), scan (+dinv), atomic-free fill.
// ---------------------------------------------------------------------------
__global__ void count_rank_kernel(const int* __restrict__ dst, int* __restrict__ cnt,
                                  int* __restrict__ rank, int E)
{
    int e = blockIdx.x * 256 + threadIdx.x;
    if (e < E) rank[e] = atomicAdd(&cnt[dst[e]], 1);
}

__global__ void scan_local(const int* __restrict__ cnt, int* __restrict__ rowptr,
                           int* __restrict__ bsum, float* __restrict__ dinv, int n)
{
    __shared__ int sd[1024];
    const int tid = threadIdx.x;
    const int i = blockIdx.x * 1024 + tid;
    int v = (i < n) ? cnt[i] : 0;
    if (i < n) dinv[i] = rsqrtf((float)v + 1.0f);
    sd[tid] = v;
    __syncthreads();
    for (int off = 1; off < 1024; off <<= 1) {
        int t = (tid >= off) ? sd[tid - off] : 0;
        __syncthreads();
        sd[tid] += t;
        __syncthreads();
    }
    if (i < n) rowptr[i + 1] = sd[tid];
    if (tid == 1023) bsum[blockIdx.x] = sd[1023];
}

__global__ void scan_bsum(int* __restrict__ bsum, int nb)
{
    const int lane = threadIdx.x;  // 64 threads, nb <= 64
    int orig = (lane < nb) ? bsum[lane] : 0;
    int v = orig;
#pragma unroll
    for (int off = 1; off < 64; off <<= 1) {
        int t = __shfl_up(v, off);
        if (lane >= off) v += t;
    }
    if (lane < nb) bsum[lane] = v - orig;  // exclusive prefix
}

__global__ void scan_add(int* __restrict__ rowptr, const int* __restrict__ bsum, int n)
{
    const int i = blockIdx.x * 1024 + threadIdx.x;
    if (i < n) rowptr[i + 1] += bsum[blockIdx.x];
    if (i == 0) rowptr[0] = 0;
}

__global__ void fill_kernel(const int* __restrict__ src, const int* __restrict__ dst,
                            const float* __restrict__ dinv, const int* __restrict__ rowptr,
                            const int* __restrict__ rank, int2* __restrict__ csr, int E)
{
    int e = blockIdx.x * 256 + threadIdx.x;
    if (e < E) {
        const int d = dst[e], s = src[e];
        const int pos = rowptr[d] + rank[e];
        int2 p;
        p.x = s;
        p.y = __float_as_int(dinv[s] * dinv[d]);
        csr[pos] = p;
    }
}

// ---------------------------------------------------------------------------
// Aggregation (gather over CSR, bf16 rows): ah = h*snorm + sum h[src]*w
// 32 threads/node (ushort4 lanes = 8B), 8 nodes/block, 4-edge unroll.
// fp32 accumulate, bf16 output (feeds MFMA A directly).
// ---------------------------------------------------------------------------
#define FMAB(A, Wt, U) { A.x = fmaf(Wt, bf2f(U.x), A.x); A.y = fmaf(Wt, bf2f(U.y), A.y); \
                         A.z = fmaf(Wt, bf2f(U.z), A.z); A.w = fmaf(Wt, bf2f(U.w), A.w); }

__global__ __launch_bounds__(256)
void agg_kernel(const ushort4* __restrict__ hb, const int2* __restrict__ csr,
                const int* __restrict__ rowptr, const float* __restrict__ dinv,
                ushort4* __restrict__ ahb, int n)
{
    const int node = blockIdx.x * 8 + (threadIdx.x >> 5);
    if (node >= n) return;
    const int lane = threadIdx.x & 31;  // ushort4 index within the 128-wide row

    const float di = dinv[node];
    const float sw = di * di;
    const ushort4 sv = hb[(size_t)node * 32 + lane];
    float4 a0, a1;
    a0.x = bf2f(sv.x) * sw; a0.y = bf2f(sv.y) * sw;
    a0.z = bf2f(sv.z) * sw; a0.w = bf2f(sv.w) * sw;
    a1.x = 0.f; a1.y = 0.f; a1.z = 0.f; a1.w = 0.f;

    const int beg = rowptr[node], end = rowptr[node + 1];
    int s = beg;
    for (; s + 4 <= end; s += 4) {
        const int2 e0 = csr[s+0], e1 = csr[s+1], e2 = csr[s+2], e3 = csr[s+3];
        const ushort4 v0 = hb[(size_t)e0.x * 32 + lane];
        const ushort4 v1 = hb[(size_t)e1.x * 32 + lane];
        const ushort4 v2 = hb[(size_t)e2.x * 32 + lane];
        const ushort4 v3 = hb[(size_t)e3.x * 32 + lane];
        FMAB(a0, __int_as_float(e0.y), v0); FMAB(a1, __int_as_float(e1.y), v1);
        FMAB(a0, __int_as_float(e2.y), v2); FMAB(a1, __int_as_float(e3.y), v3);
    }
    for (; s < end; ++s) {
        const int2 e0 = csr[s];
        const ushort4 v = hb[(size_t)e0.x * 32 + lane];
        FMAB(a0, __int_as_float(e0.y), v);
    }
    ushort4 q;
    q.x = f2bf(a0.x + a1.x); q.y = f2bf(a0.y + a1.y);
    q.z = f2bf(a0.z + a1.z); q.w = f2bf(a0.w + a1.w);
    ahb[(size_t)node * 32 + lane] = q;
}

// ---------------------------------------------------------------------------
// pooling over sorted batch; graph bounds via inline binary search.
// Stage 1: 16 fixed chunks per graph; stage 2: combine.
// h is bf16.
// ---------------------------------------------------------------------------
__device__ __forceinline__ int lb_batch(const int* __restrict__ batch, int n, int t)
{
    int lo = 0, hi = n;
    while (lo < hi) { int mid = (lo + hi) >> 1; if (batch[mid] < t) lo = mid + 1; else hi = mid; }
    return lo;
}

__global__ void pool_partial(const unsigned short* __restrict__ h, const float* __restrict__ aw,
                             const int* __restrict__ batch, int n, float* __restrict__ ps,
                             float* __restrict__ pm, float* __restrict__ pw)
{
    const int g = blockIdx.x >> 4;
    const int c = blockIdx.x & (POOL_NC - 1);
    const int f = threadIdx.x;  // 128 threads
    const int beg = lb_batch(batch, n, g), end = lb_batch(batch, n, g + 1);
    const int len = end - beg;
    const int cbeg = beg + (int)(((long long)len * c) / POOL_NC);
    const int cend = beg + (int)(((long long)len * (c + 1)) / POOL_NC);
    float s = 0.f, m = -FLT_MAX, w = 0.f;
    for (int node = cbeg; node < cend; ++node) {
        const float v = bf2f(h[(size_t)node * 128 + f]);
        const float a = aw[node];
        s += v;
        m = fmaxf(m, v);
        w = fmaf(v, a, w);
    }
    const size_t idx = ((size_t)g * POOL_NC + c) * 128 + f;
    ps[idx] = s; pm[idx] = m; pw[idx] = w;
}

__global__ void pool_final(const float* __restrict__ ps, const float* __restrict__ pm,
                           const float* __restrict__ pw, const int* __restrict__ batch,
                           int n, float* __restrict__ comb)
{
    const int g = blockIdx.x;
    const int f = threadIdx.x;  // 128 threads
    float s = 0.f, m = -FLT_MAX, w = 0.f;
#pragma unroll
    for (int c = 0; c < POOL_NC; ++c) {
        const size_t idx = ((size_t)g * POOL_NC + c) * 128 + f;
        s += ps[idx];
        m = fmaxf(m, pm[idx]);
        w += pw[idx];
    }
    float cn = (float)(lb_batch(batch, n, g + 1) - lb_batch(batch, n, g));
    if (cn < 1.f) cn = 1.f;
    comb[(size_t)g * 512 + f]       = s / cn;
    comb[(size_t)g * 512 + 128 + f] = m;
    comb[(size_t)g * 512 + 256 + f] = s / cn;
    comb[(size_t)g * 512 + 384 + f] = w / cn;
}

// ---------------------------------------------------------------------------
// classifier head GEMM: grid = G * (M/64); block 256 = 64 cols x 4 k-quarters.
// ---------------------------------------------------------------------------
template<int K, int M, bool DO_BN, bool DO_GELU>
__global__ __launch_bounds__(256)
void rowgemm2(const float* __restrict__ X, const float* __restrict__ W,
              const float* __restrict__ bias, const float* __restrict__ gam,
              const float* __restrict__ beta, float* __restrict__ Y)
{
    constexpr int NC = M / 64;
    constexpr int KQ = K / 4;
    const int row = blockIdx.x / NC;
    const int lane = threadIdx.x & 63;
    const int c = (blockIdx.x % NC) * 64 + lane;
    const int q = threadIdx.x >> 6;  // k-quarter 0..3

    const float* __restrict__ xq = X + (size_t)row * K + q * KQ;
    const float* __restrict__ wq = W + (size_t)(q * KQ) * M + c;

    float a0 = 0.f, a1 = 0.f, a2 = 0.f, a3 = 0.f;
#pragma unroll 4
    for (int k = 0; k < KQ; k += 4) {
        const float4 xv = *reinterpret_cast<const float4*>(xq + k);
        a0 = fmaf(xv.x, wq[(size_t)(k + 0) * M], a0);
        a1 = fmaf(xv.y, wq[(size_t)(k + 1) * M], a1);
        a2 = fmaf(xv.z, wq[(size_t)(k + 2) * M], a2);
        a3 = fmaf(xv.w, wq[(size_t)(k + 3) * M], a3);
    }
    __shared__ float part[4][64];
    part[q][lane] = (a0 + a1) + (a2 + a3);
    __syncthreads();
    if (q == 0) {
        float v = (part[0][lane] + part[1][lane]) + (part[2][lane] + part[3][lane]);
        if (DO_BN) { const float g = gam[c]; const float sc = g * BNS_F; v = v * sc + (bias[c] * sc + beta[c]); }
        else       { v = v + bias[c]; }
        if (DO_GELU) v = gelu_f(v);
        Y[(size_t)row * M + c] = v;
    }
}

// final layer: [G,64] @ [64,4] + bias; one wave per row, shuffle reduce
__global__ void rowgemm_final(const float* __restrict__ X, const float* __restrict__ W,
                              const float* __restrict__ bias, float* __restrict__ Y)
{
    const int row = blockIdx.x;
    const int lane = threadIdx.x;  // 64
    const float xv = X[(size_t)row * 64 + lane];
    const float4 wr = *reinterpret_cast<const float4*>(W + lane * 4);
    float a0 = xv * wr.x, a1 = xv * wr.y, a2 = xv * wr.z, a3 = xv * wr.w;
#pragma unroll
    for (int off = 32; off; off >>= 1) {
        a0 += __shfl_xor(a0, off);
        a1 += __shfl_xor(a1, off);
        a2 += __shfl_xor(a2, off);
        a3 += __shfl_xor(a3, off);
    }
    if (lane == 0) {
        Y[(size_t)row * 4 + 0] = a0 + bias[0];
        Y[(size_t)row * 4 + 1] = a1 + bias[1];
        Y[(size_t)row * 4 + 2] = a2 + bias[2];
        Y[(size_t)row * 4 + 3] = a3 + bias[3];
    }
}

// ---------------------------------------------------------------------------
extern "C" void kernel_launch(void* const* d_in, const int* in_sizes, int n_in,
                              void* d_out, int out_size, void* d_ws, size_t ws_size,
                              hipStream_t stream)
{
    const float* x     = (const float*)d_in[0];
    const int*   ei    = (const int*)d_in[1];
    const int*   batch = (const int*)d_in[2];
    const float* W1  = (const float*)d_in[3];
    const float* b1  = (const float*)d_in[4];
    const float* g1  = (const float*)d_in[5];
    const float* be1 = (const float*)d_in[6];
    const float* W2  = (const float*)d_in[7];
    const float* b2  = (const float*)d_in[8];
    const float* g2  = (const float*)d_in[9];
    const float* be2 = (const float*)d_in[10];
    const float* Wg  = (const float*)d_in[11];
    const float* bg  = (const float*)d_in[12];
    const float* gg  = (const float*)d_in[13];
    const float* bgg = (const float*)d_in[14];
    const float* Wa1 = (const float*)d_in[15];
    const float* ba1 = (const float*)d_in[16];
    const float* Wa2 = (const float*)d_in[17];
    const float* ba2 = (const float*)d_in[18];
    const float* Wc1 = (const float*)d_in[19];
    const float* bc1 = (const float*)d_in[20];
    const float* gc1 = (const float*)d_in[21];
    const float* bec1= (const float*)d_in[22];
    const float* Wc2 = (const float*)d_in[23];
    const float* bc2 = (const float*)d_in[24];
    const float* gc2 = (const float*)d_in[25];
    const float* bec2= (const float*)d_in[26];
    const float* Wc3 = (const float*)d_in[27];
    const float* bc3 = (const float*)d_in[28];
    const float* gc3 = (const float*)d_in[29];
    const float* bec3= (const float*)d_in[30];
    const float* Wc4 = (const float*)d_in[31];
    const float* bc4 = (const float*)d_in[32];
    float* out = (float*)d_out;

    const int N = in_sizes[0] / 128;
    const int E = in_sizes[1] / 2;
    const int G = GGRAPHS;

    // workspace carve-up
    size_t off = 0;
    auto alloc = [&](size_t bytes) -> void* {
        void* p = (char*)d_ws + off;
        off += (bytes + 255) & ~(size_t)255;
        return p;
    };
    unsigned short* hAb   = (unsigned short*)alloc((size_t)N * 128 * 2);  // bf16 proj1 out
    unsigned short* hbf   = (unsigned short*)alloc((size_t)N * 128 * 2);  // bf16 h (resident)
    unsigned short* ahb   = (unsigned short*)alloc((size_t)N * 128 * 2);  // bf16 agg out
    unsigned short* Wt1   = (unsigned short*)alloc(128 * 128 * 2);
    unsigned short* Wt2   = (unsigned short*)alloc(128 * 128 * 2);
    unsigned short* Wtg   = (unsigned short*)alloc(3 * 128 * 128 * 2);
    unsigned short* Wta1  = (unsigned short*)alloc(64 * 128 * 2);
    float*   aw     = (float*)alloc((size_t)N * 4);
    float*   dinv   = (float*)alloc((size_t)N * 4);
    int*     cnt    = (int*)alloc((size_t)N * 4);
    int*     rank   = (int*)alloc((size_t)E * 4);
    int*     rowptr = (int*)alloc((size_t)(N + 1) * 4);
    int*     bsum   = (int*)alloc(64 * 4);
    int2*    csr    = (int2*)alloc((size_t)E * 8);
    float*   comb   = (float*)alloc((size_t)G * 512 * 4);
    float*   ps     = (float*)alloc((size_t)G * POOL_NC * 128 * 4);
    float*   pm     = (float*)alloc((size_t)G * POOL_NC * 128 * 4);
    float*   pw     = (float*)alloc((size_t)G * POOL_NC * 128 * 4);
    float*   z1     = (float*)alloc((size_t)G * 256 * 4);
    float*   z2     = (float*)alloc((size_t)G * 128 * 4);
    float*   z3     = (float*)alloc((size_t)G * 64 * 4);
    (void)ws_size;

    const int* e_src = ei;
    const int* e_dst = ei + E;

    // ---- weight prep (single kernel) ----
    transpose_all_kernel<<<352, 256, 0, stream>>>(W1, W2, Wg, Wa1, Wt1, Wt2, Wtg, Wta1);

    // ---- CSR build over dst (reused by all 3 GCN layers) ----
    hipMemsetAsync(cnt, 0, (size_t)N * 4, stream);
    count_rank_kernel<<<(E + 255) / 256, 256, 0, stream>>>(e_dst, cnt, rank, E);
    const int nb = (N + 1023) / 1024;
    scan_local<<<nb, 1024, 0, stream>>>(cnt, rowptr, bsum, dinv, N);
    scan_bsum<<<1, 64, 0, stream>>>(bsum, nb);
    scan_add<<<nb, 1024, 0, stream>>>(rowptr, bsum, N);
    fill_kernel<<<(E + 255) / 256, 256, 0, stream>>>(e_src, e_dst, dinv, rowptr, rank, csr, E);

    const int rowblocks = (N + 63) / 64;   // 782

    // ---- input projection (fp32 x converted in-kernel) ----
    gemm_mfma<128, true, true, true, false, false><<<rowblocks, 256, 0, stream>>>(
        x, Wt1, b1, g1, be1, nullptr, hAb, nullptr, nullptr, nullptr, N);
    gemm_mfma<128, false, true, true, false, false><<<rowblocks, 256, 0, stream>>>(
        hAb, Wt2, b2, g2, be2, nullptr, hbf, nullptr, nullptr, nullptr, N);

    // ---- GCN layers: agg (bf16) -> MFMA gemm, bf16 in-place residual ----
    for (int l = 0; l < 3; ++l) {
        agg_kernel<<<(N + 7) / 8, 256, 0, stream>>>(
            (const ushort4*)hbf, csr, rowptr, dinv, (ushort4*)ahb, N);
        gemm_mfma<128, false, true, true, true, false><<<rowblocks, 256, 0, stream>>>(
            ahb, Wtg + (size_t)l * 16384, bg + (size_t)l * 128,
            gg + (size_t)l * 128, bgg + (size_t)l * 128, hbf, hbf,
            nullptr, nullptr, nullptr, N);
    }

    // ---- attention weights (fused: gelu(h@Wa1+ba1)@Wa2+ba2 -> tanh) ----
    gemm_mfma<64, false, false, true, false, true><<<rowblocks, 256, 0, stream>>>(
        hbf, Wta1, ba1, nullptr, nullptr, nullptr, nullptr, Wa2, ba2, aw, N);

    // ---- pooling (h = hbf bf16; bounds inlined) ----
    pool_partial<<<G * POOL_NC, 128, 0, stream>>>(hbf, aw, batch, N, ps, pm, pw);
    pool_final<<<G, 128, 0, stream>>>(ps, pm, pw, batch, N, comb);

    // ---- classifier head (fp32, tiny) ----
    rowgemm2<512, 256, true, true><<<G * 4, 256, 0, stream>>>(comb, Wc1, bc1, gc1, bec1, z1);
    rowgemm2<256, 128, true, true><<<G * 2, 256, 0, stream>>>(z1, Wc2, bc2, gc2, bec2, z2);
    rowgemm2<128, 64,  true, true><<<G * 1, 256, 0, stream>>>(z2, Wc3, bc3, gc3, bec3, z3);
    rowgemm_final<<<G, 64, 0, stream>>>(z3, Wc4, bc4, out);
}